// Round 3
// baseline (437.715 us; speedup 1.0000x reference)
//
#include <hip/hip_runtime.h>
#include <stdint.h>

#define FD 128   // feature dim
#define NG 8     // graphs
#define NC 10    // classes

typedef __attribute__((ext_vector_type(8))) short bf16x8;
typedef __attribute__((ext_vector_type(4))) float f32x4;

__device__ __forceinline__ float bf2f(uint16_t u){
    union { uint32_t i; float f; } v; v.i = ((uint32_t)u) << 16; return v.f;
}
__device__ __forceinline__ uint16_t f2bf(float f){
    union { float f; uint32_t i; } v; v.f = f;
    uint32_t r = v.i + 0x7fff + ((v.i >> 16) & 1);   // round-to-nearest-even
    return (uint16_t)(r >> 16);
}

// ---- split W1/W2 (f32) into bf16 hi/lo, laid out in MFMA B-fragment order ----
// Wf[((kk*8+n)*64+lane)*8+j] = W[k][col], k=kk*32+(lane>>4)*8+j, col=n*16+(lane&15)
__global__ void k_prep_w(const float* __restrict__ W1, const float* __restrict__ W2,
                         uint16_t* WfHi1, uint16_t* WfLo1, uint16_t* WfHi2, uint16_t* WfLo2){
    int id = blockIdx.x*256 + threadIdx.x;     // 0..32767
    int w = id >> 14;          // 0 -> W1, 1 -> W2
    int r = id & 16383;
    int j = r & 7, frag = r >> 3;
    int lane = frag & 63, t2 = frag >> 6;
    int n = t2 & 7, kk = t2 >> 3;
    int k = kk*32 + (lane>>4)*8 + j;
    int col = n*16 + (lane&15);
    float v = (w ? W2 : W1)[k*128 + col];
    uint16_t hi = f2bf(v);
    uint16_t lo = f2bf(v - bf2f(hi));
    (w ? WfHi2 : WfHi1)[r] = hi;
    (w ? WfLo2 : WfLo1)[r] = lo;
}

// ---- degree counting ----
__global__ void k_degree(const int* __restrict__ ei, int E, int* deg_out, int* deg_in){
    int e = blockIdx.x*256 + threadIdx.x;
    if (e < E){
        atomicAdd(&deg_out[ei[e]], 1);
        atomicAdd(&deg_in[ei[E+e]], 1);
    }
}

__global__ void k_bsum(const int* __restrict__ deg_in, int N, int* __restrict__ bsum){
    __shared__ int s[256];
    int t = threadIdx.x, i = blockIdx.x*256 + t;
    s[t] = (i < N) ? deg_in[i] : 0;
    __syncthreads();
    for (int o=128;o>0;o>>=1){ if (t<o) s[t]+=s[t+o]; __syncthreads(); }
    if (t==0) bsum[blockIdx.x] = s[0];
}

__global__ void k_scan_bsum(const int* __restrict__ bsum, int nb, int* __restrict__ boff,
                            int* __restrict__ row_off, int N, int E){
    __shared__ int s[256];
    int t = threadIdx.x;
    int v = (t < nb) ? bsum[t] : 0;
    s[t] = v; __syncthreads();
    for (int o=1;o<256;o<<=1){
        int x = (t>=o) ? s[t-o] : 0;
        __syncthreads(); s[t]+=x; __syncthreads();
    }
    boff[t] = s[t]-v;
    if (t==0) row_off[N] = E;
}

__global__ void k_scan_write(const int* __restrict__ deg_in, int N,
                             const int* __restrict__ boff, int* __restrict__ row_off){
    __shared__ int s[256];
    int t = threadIdx.x, i = blockIdx.x*256 + t;
    int v = (i < N) ? deg_in[i] : 0;
    s[t] = v; __syncthreads();
    for (int o=1;o<256;o<<=1){
        int x = (t>=o) ? s[t-o] : 0;
        __syncthreads(); s[t]+=x; __syncthreads();
    }
    if (i < N) row_off[i] = boff[blockIdx.x] + s[t] - v;
}

__global__ void k_fill(const int* __restrict__ ei, int E, const int* __restrict__ row_off,
                       int* __restrict__ cursor, int* __restrict__ csr_src){
    int e = blockIdx.x*256 + threadIdx.x;
    if (e < E){
        int d = ei[E+e];
        int p = row_off[d] + atomicAdd(&cursor[d], 1);
        csr_src[p] = ei[e];
    }
}

// ---- GEMM: tmp[row,:] = bf16( (A[row,:] @ W) * rsqrt(max(deg_out[row],1)) ) ----
// amode=0: A is f32 (split into hi+lo, 3 MFMAs). amode=1: A is bf16 (2 MFMAs).
// Block 256 thr = 4 waves, 64 rows; wave: 16 rows x 128 cols, K=128.
__global__ __launch_bounds__(256) void k_gemm(const void* __restrict__ A,
        const uint16_t* __restrict__ WfHi, const uint16_t* __restrict__ WfLo,
        const int* __restrict__ deg_out, uint16_t* __restrict__ out, int nrows,
        int amode){
    int t = threadIdx.x;
    int wave = t>>6, lane = t&63, quad = lane>>4, low = lane&15;

    int rowA  = blockIdx.x*64 + wave*16 + low;
    int rowAc = min(rowA, nrows-1);

    bf16x8 ah[4], al[4];
    if (amode){
        const uint16_t* arow = (const uint16_t*)A + (size_t)rowAc*FD;
        #pragma unroll
        for (int kk=0;kk<4;kk++)
            ah[kk] = *(const bf16x8*)(arow + kk*32 + quad*8);
    } else {
        const float* arow = (const float*)A + (size_t)rowAc*FD;
        #pragma unroll
        for (int kk=0;kk<4;kk++){
            f32x4 f0 = *(const f32x4*)(arow + kk*32 + quad*8);
            f32x4 f1 = *(const f32x4*)(arow + kk*32 + quad*8 + 4);
            #pragma unroll
            for (int j=0;j<4;j++){
                float f = f0[j]; uint16_t h = f2bf(f);
                ah[kk][j] = (short)h; al[kk][j] = (short)f2bf(f - bf2f(h));
            }
            #pragma unroll
            for (int j=0;j<4;j++){
                float f = f1[j]; uint16_t h = f2bf(f);
                ah[kk][j+4] = (short)h; al[kk][j+4] = (short)f2bf(f - bf2f(h));
            }
        }
    }

    f32x4 acc[8];
    #pragma unroll
    for (int n=0;n<8;n++) acc[n] = (f32x4){0.f,0.f,0.f,0.f};

    #pragma unroll
    for (int kk=0;kk<4;kk++){
        #pragma unroll
        for (int n=0;n<8;n++){
            size_t fo = ((size_t)((kk*8+n)*64 + lane))*8;
            bf16x8 bh = *(const bf16x8*)(WfHi + fo);
            bf16x8 bl = *(const bf16x8*)(WfLo + fo);
            acc[n] = __builtin_amdgcn_mfma_f32_16x16x32_bf16(ah[kk], bh, acc[n], 0, 0, 0);
            if (!amode)
                acc[n] = __builtin_amdgcn_mfma_f32_16x16x32_bf16(al[kk], bh, acc[n], 0, 0, 0);
            acc[n] = __builtin_amdgcn_mfma_f32_16x16x32_bf16(ah[kk], bl, acc[n], 0, 0, 0);
        }
    }

    // C/D: col = lane&15, row = quad*4 + reg
    int rbase = blockIdx.x*64 + wave*16 + quad*4;
    float sc[4]; int rok[4];
    #pragma unroll
    for (int r=0;r<4;r++){
        int row = rbase + r;
        rok[r] = row < nrows;
        int dg = rok[r] ? deg_out[row] : 1;
        sc[r] = rsqrtf((float)max(dg,1));
    }
    #pragma unroll
    for (int n=0;n<8;n++){
        int col = n*16 + low;
        #pragma unroll
        for (int r=0;r<4;r++){
            if (rok[r]) out[(size_t)(rbase+r)*FD + col] = f2bf(acc[n][r]*sc[r]);
        }
    }
}

// ---- SpMM: h[dst,:] = relu( (sum_src tmp[src,:]) * rsqrt(max(indeg,1)) + bias ) ----
// One wave per dst node; lane owns 2 features (4 B) -> each src row is one
// coalesced 256 B read. Indices batch-loaded and shfl-broadcast.
__global__ __launch_bounds__(256) void k_spmm(const uint16_t* __restrict__ tmp,
        const int* __restrict__ row_off, const int* __restrict__ csr_src,
        const float* __restrict__ bias, uint16_t* __restrict__ hout, int N){
    int node = blockIdx.x*4 + (threadIdx.x>>6);
    int lane = threadIdx.x & 63;
    if (node >= N) return;
    int e0 = row_off[node], e1 = row_off[node+1];
    float a0 = 0.f, a1 = 0.f;
    for (int base = e0; base < e1; base += 64){
        int my = 0;
        if (base + lane < e1) my = csr_src[base + lane];
        int cnt = min(64, e1 - base);
        for (int j = 0; j < cnt; j++){
            int s = __shfl(my, j);
            uint32_t p = *(const uint32_t*)(tmp + (size_t)s*FD + lane*2);
            a0 += bf2f((uint16_t)(p & 0xffff));
            a1 += bf2f((uint16_t)(p >> 16));
        }
    }
    float isq = rsqrtf((float)max(e1 - e0, 1));
    float r0 = fmaxf(a0*isq + bias[lane*2],   0.f);
    float r1 = fmaxf(a1*isq + bias[lane*2+1], 0.f);
    uint32_t o = (uint32_t)f2bf(r0) | ((uint32_t)f2bf(r1) << 16);
    *(uint32_t*)(hout + (size_t)node*FD + lane*2) = o;
}

// ---- per-graph feature sums (node2graph sorted -> run-length accumulate) ----
__global__ __launch_bounds__(128) void k_pool(const uint16_t* __restrict__ h,
        const int* __restrict__ n2g, int N, float* __restrict__ pool){
    __shared__ float sacc[NG*FD];
    int t = threadIdx.x;            // feature column
    for (int g=0; g<NG; g++) sacc[g*FD+t] = 0.f;
    __syncthreads();
    int start = blockIdx.x*256;
    float racc = 0.f; int rg = -1;
    for (int i=0;i<256;i++){
        int node = start + i;
        if (node >= N) break;
        int g = n2g[node];
        if (g != rg){ if (rg >= 0) sacc[rg*FD+t] += racc; racc = 0.f; rg = g; }
        racc += bf2f(h[(size_t)node*FD + t]);
    }
    if (rg >= 0) sacc[rg*FD+t] += racc;
    __syncthreads();
    for (int g=0; g<NG; g++){
        float v = sacc[g*FD+t];
        if (v != 0.f) atomicAdd(&pool[g*FD+t], v);
    }
}

// ---- mean, linear, softmax -> 80 f32 ----
__global__ __launch_bounds__(128) void k_final(const float* __restrict__ pool,
        const int* __restrict__ n2g, int N, const float* __restrict__ Wl,
        const float* __restrict__ bl, float* __restrict__ out){
    __shared__ int ub[NG+1];
    __shared__ float logits[NG][NC];
    int t = threadIdx.x;
    if (t <= NG){
        int lo = 0, hi = N;                 // first i with n2g[i] >= t
        while (lo < hi){ int mid = (lo+hi)>>1; if (n2g[mid] < t) lo = mid+1; else hi = mid; }
        ub[t] = lo;
    }
    __syncthreads();
    if (t < NG*NC){
        int g = t/NC, c = t%NC;
        float cnt = (float)max(ub[g+1]-ub[g], 1);
        float inv = 1.f/cnt;
        float acc = bl[c];
        for (int d=0; d<FD; d++)
            acc += pool[g*FD+d]*inv * Wl[d*NC+c];
        logits[g][c] = acc;
    }
    __syncthreads();
    if (t < NG*NC){
        int g = t/NC, c = t%NC;
        float m = -1e30f;
        for (int i=0;i<NC;i++) m = fmaxf(m, logits[g][i]);
        float ssum = 0.f;
        for (int i=0;i<NC;i++) ssum += expf(logits[g][i]-m);
        out[t] = expf(logits[g][c]-m)/ssum;
    }
}

extern "C" void kernel_launch(void* const* d_in, const int* in_sizes, int n_in,
                              void* d_out, int out_size, void* d_ws, size_t ws_size,
                              hipStream_t stream) {
    const float* x   = (const float*)d_in[0];
    const int*   ei  = (const int*)d_in[1];
    const int*   n2g = (const int*)d_in[2];
    const float* W1  = (const float*)d_in[3];
    const float* b1  = (const float*)d_in[4];
    const float* W2  = (const float*)d_in[5];
    const float* b2  = (const float*)d_in[6];
    const float* Wl  = (const float*)d_in[7];
    const float* bl  = (const float*)d_in[8];
    float* outp = (float*)d_out;

    int N = in_sizes[2];
    int E = in_sizes[1] / 2;

    char* w = (char*)d_ws;
    size_t off = 0;
    auto alloc = [&](size_t bytes)->char*{ char* p = w + off; off += (bytes + 255) & ~(size_t)255; return p; };
    int*      deg_out = (int*)alloc((size_t)N*4);
    int*      deg_in  = (int*)alloc((size_t)N*4);
    int*      cursor  = (int*)alloc((size_t)N*4);
    float*    pool    = (float*)alloc((size_t)NG*FD*4);
    size_t zbytes = off;                         // zeroed region
    int*      bsum    = (int*)alloc(256*4);
    int*      boff    = (int*)alloc(256*4);
    int*      row_off = (int*)alloc((size_t)(N+1)*4);
    int*      csr     = (int*)alloc((size_t)E*4);
    uint16_t* WfHi1   = (uint16_t*)alloc(16384*2);
    uint16_t* WfLo1   = (uint16_t*)alloc(16384*2);
    uint16_t* WfHi2   = (uint16_t*)alloc(16384*2);
    uint16_t* WfLo2   = (uint16_t*)alloc(16384*2);
    uint16_t* tmp     = (uint16_t*)alloc((size_t)N*FD*2);
    uint16_t* hb      = (uint16_t*)alloc((size_t)N*FD*2);
    (void)ws_size;

    hipMemsetAsync(d_ws, 0, zbytes, stream);

    int eb = (E + 255)/256;
    int nb = (N + 255)/256;
    k_prep_w    <<<128, 256, 0, stream>>>(W1, W2, WfHi1, WfLo1, WfHi2, WfLo2);
    k_degree    <<<eb, 256, 0, stream>>>(ei, E, deg_out, deg_in);
    k_bsum      <<<nb, 256, 0, stream>>>(deg_in, N, bsum);
    k_scan_bsum <<<1,  256, 0, stream>>>(bsum, nb, boff, row_off, N, E);
    k_scan_write<<<nb, 256, 0, stream>>>(deg_in, N, boff, row_off);
    k_fill      <<<eb, 256, 0, stream>>>(ei, E, row_off, cursor, csr);

    int gb = (N + 63)/64;
    int sb = (N + 3)/4;
    k_gemm <<<gb, 256, 0, stream>>>(x,  WfHi1, WfLo1, deg_out, tmp, N, 0);
    k_spmm <<<sb, 256, 0, stream>>>(tmp, row_off, csr, b1, hb, N);
    k_gemm <<<gb, 256, 0, stream>>>(hb, WfHi2, WfLo2, deg_out, tmp, N, 1);
    k_spmm <<<sb, 256, 0, stream>>>(tmp, row_off, csr, b2, hb, N);
    k_pool <<<nb, 128, 0, stream>>>(hb, n2g, N, pool);
    k_final<<<1,  128, 0, stream>>>(pool, n2g, N, Wl, bl, outp);
}

// Round 4
// 323.331 us; speedup vs baseline: 1.3538x; 1.3538x over previous
//
#include <hip/hip_runtime.h>
#include <stdint.h>

#define FD 128   // feature dim
#define NG 8     // graphs
#define NC 10    // classes

typedef __attribute__((ext_vector_type(8))) short bf16x8;
typedef __attribute__((ext_vector_type(4))) float f32x4;

__device__ __forceinline__ float bf2f(uint16_t u){
    union { uint32_t i; float f; } v; v.i = ((uint32_t)u) << 16; return v.f;
}
__device__ __forceinline__ uint16_t f2bf(float f){
    union { float f; uint32_t i; } v; v.f = f;
    uint32_t r = v.i + 0x7fff + ((v.i >> 16) & 1);   // round-to-nearest-even
    return (uint16_t)(r >> 16);
}

// ---- split W1/W2 (f32) into bf16 hi/lo, laid out in MFMA B-fragment order ----
// Wf[((kk*8+n)*64+lane)*8+j] = W[k][col], k=kk*32+(lane>>4)*8+j, col=n*16+(lane&15)
__global__ void k_prep_w(const float* __restrict__ W1, const float* __restrict__ W2,
                         uint16_t* WfHi1, uint16_t* WfLo1, uint16_t* WfHi2, uint16_t* WfLo2){
    int id = blockIdx.x*256 + threadIdx.x;     // 0..32767
    int w = id >> 14;          // 0 -> W1, 1 -> W2
    int r = id & 16383;
    int j = r & 7, frag = r >> 3;
    int lane = frag & 63, t2 = frag >> 6;
    int n = t2 & 7, kk = t2 >> 3;
    int k = kk*32 + (lane>>4)*8 + j;
    int col = n*16 + (lane&15);
    float v = (w ? W2 : W1)[k*128 + col];
    uint16_t hi = f2bf(v);
    uint16_t lo = f2bf(v - bf2f(hi));
    (w ? WfHi2 : WfHi1)[r] = hi;
    (w ? WfLo2 : WfLo1)[r] = lo;
}

// ---- degree counting ----
__global__ void k_degree(const int* __restrict__ ei, int E, int* deg_out, int* deg_in){
    int e = blockIdx.x*256 + threadIdx.x;
    if (e < E){
        atomicAdd(&deg_out[ei[e]], 1);
        atomicAdd(&deg_in[ei[E+e]], 1);
    }
}

__global__ void k_bsum(const int* __restrict__ deg_in, int N, int* __restrict__ bsum){
    __shared__ int s[256];
    int t = threadIdx.x, i = blockIdx.x*256 + t;
    s[t] = (i < N) ? deg_in[i] : 0;
    __syncthreads();
    for (int o=128;o>0;o>>=1){ if (t<o) s[t]+=s[t+o]; __syncthreads(); }
    if (t==0) bsum[blockIdx.x] = s[0];
}

__global__ void k_scan_bsum(const int* __restrict__ bsum, int nb, int* __restrict__ boff,
                            int* __restrict__ row_off, int N, int E){
    __shared__ int s[256];
    int t = threadIdx.x;
    int v = (t < nb) ? bsum[t] : 0;
    s[t] = v; __syncthreads();
    for (int o=1;o<256;o<<=1){
        int x = (t>=o) ? s[t-o] : 0;
        __syncthreads(); s[t]+=x; __syncthreads();
    }
    boff[t] = s[t]-v;
    if (t==0) row_off[N] = E;
}

__global__ void k_scan_write(const int* __restrict__ deg_in, int N,
                             const int* __restrict__ boff, int* __restrict__ row_off){
    __shared__ int s[256];
    int t = threadIdx.x, i = blockIdx.x*256 + t;
    int v = (i < N) ? deg_in[i] : 0;
    s[t] = v; __syncthreads();
    for (int o=1;o<256;o<<=1){
        int x = (t>=o) ? s[t-o] : 0;
        __syncthreads(); s[t]+=x; __syncthreads();
    }
    if (i < N) row_off[i] = boff[blockIdx.x] + s[t] - v;
}

__global__ void k_fill(const int* __restrict__ ei, int E, const int* __restrict__ row_off,
                       int* __restrict__ cursor, int* __restrict__ csr_src){
    int e = blockIdx.x*256 + threadIdx.x;
    if (e < E){
        int d = ei[E+e];
        int p = row_off[d] + atomicAdd(&cursor[d], 1);
        csr_src[p] = ei[e];
    }
}

// ---- GEMM: tmp[row,:] = bf16( (A[row,:] @ W) * rsqrt(max(deg_out[row],1)) ) ----
// amode=0: A is f32 (split hi/lo, 3 MFMAs). amode=1: A is bf16 (2 MFMAs).
__global__ __launch_bounds__(256) void k_gemm(const void* __restrict__ A,
        const uint16_t* __restrict__ WfHi, const uint16_t* __restrict__ WfLo,
        const int* __restrict__ deg_out, uint16_t* __restrict__ out, int nrows,
        int amode){
    int t = threadIdx.x;
    int wave = t>>6, lane = t&63, quad = lane>>4, low = lane&15;

    int rowA  = blockIdx.x*64 + wave*16 + low;
    int rowAc = min(rowA, nrows-1);

    bf16x8 ah[4], al[4];
    if (amode){
        const uint16_t* arow = (const uint16_t*)A + (size_t)rowAc*FD;
        #pragma unroll
        for (int kk=0;kk<4;kk++)
            ah[kk] = *(const bf16x8*)(arow + kk*32 + quad*8);
    } else {
        const float* arow = (const float*)A + (size_t)rowAc*FD;
        #pragma unroll
        for (int kk=0;kk<4;kk++){
            f32x4 f0 = *(const f32x4*)(arow + kk*32 + quad*8);
            f32x4 f1 = *(const f32x4*)(arow + kk*32 + quad*8 + 4);
            #pragma unroll
            for (int j=0;j<4;j++){
                float f = f0[j]; uint16_t h = f2bf(f);
                ah[kk][j] = (short)h; al[kk][j] = (short)f2bf(f - bf2f(h));
            }
            #pragma unroll
            for (int j=0;j<4;j++){
                float f = f1[j]; uint16_t h = f2bf(f);
                ah[kk][j+4] = (short)h; al[kk][j+4] = (short)f2bf(f - bf2f(h));
            }
        }
    }

    f32x4 acc[8];
    #pragma unroll
    for (int n=0;n<8;n++) acc[n] = (f32x4){0.f,0.f,0.f,0.f};

    #pragma unroll
    for (int kk=0;kk<4;kk++){
        #pragma unroll
        for (int n=0;n<8;n++){
            size_t fo = ((size_t)((kk*8+n)*64 + lane))*8;
            bf16x8 bh = *(const bf16x8*)(WfHi + fo);
            bf16x8 bl = *(const bf16x8*)(WfLo + fo);
            acc[n] = __builtin_amdgcn_mfma_f32_16x16x32_bf16(ah[kk], bh, acc[n], 0, 0, 0);
            if (!amode)
                acc[n] = __builtin_amdgcn_mfma_f32_16x16x32_bf16(al[kk], bh, acc[n], 0, 0, 0);
            acc[n] = __builtin_amdgcn_mfma_f32_16x16x32_bf16(ah[kk], bl, acc[n], 0, 0, 0);
        }
    }

    // C/D: col = lane&15, row = quad*4 + reg
    int rbase = blockIdx.x*64 + wave*16 + quad*4;
    float sc[4]; int rok[4];
    #pragma unroll
    for (int r=0;r<4;r++){
        int row = rbase + r;
        rok[r] = row < nrows;
        int dg = rok[r] ? deg_out[row] : 1;
        sc[r] = rsqrtf((float)max(dg,1));
    }
    #pragma unroll
    for (int n=0;n<8;n++){
        int col = n*16 + low;
        #pragma unroll
        for (int r=0;r<4;r++){
            if (rok[r]) out[(size_t)(rbase+r)*FD + col] = f2bf(acc[n][r]*sc[r]);
        }
    }
}

// ---- SpMM: h[dst,:] = relu( (sum_src tmp[src,:]) * rsqrt(max(indeg,1)) + bias ) ----
// One wave per dst node; lane owns 2 features (4 B). 4-way batched row loads
// (indices shfl-broadcast; cnt is wave-uniform so batching is non-divergent).
__global__ __launch_bounds__(256) void k_spmm(const uint16_t* __restrict__ tmp,
        const int* __restrict__ row_off, const int* __restrict__ csr_src,
        const float* __restrict__ bias, uint16_t* __restrict__ hout, int N){
    int node = blockIdx.x*4 + (threadIdx.x>>6);
    int lane = threadIdx.x & 63;
    if (node >= N) return;
    int e0 = row_off[node], e1 = row_off[node+1];
    const uint32_t* tp = (const uint32_t*)tmp;
    float a0 = 0.f, a1 = 0.f;
    for (int base = e0; base < e1; base += 64){
        int my = 0;
        if (base + lane < e1) my = csr_src[base + lane];
        int cnt = min(64, e1 - base);
        int j = 0;
        for (; j + 4 <= cnt; j += 4){
            int s0 = __shfl(my, j);
            int s1 = __shfl(my, j+1);
            int s2 = __shfl(my, j+2);
            int s3 = __shfl(my, j+3);
            uint32_t p0 = tp[(size_t)s0*64 + lane];
            uint32_t p1 = tp[(size_t)s1*64 + lane];
            uint32_t p2 = tp[(size_t)s2*64 + lane];
            uint32_t p3 = tp[(size_t)s3*64 + lane];
            a0 += bf2f((uint16_t)(p0 & 0xffff)); a1 += bf2f((uint16_t)(p0 >> 16));
            a0 += bf2f((uint16_t)(p1 & 0xffff)); a1 += bf2f((uint16_t)(p1 >> 16));
            a0 += bf2f((uint16_t)(p2 & 0xffff)); a1 += bf2f((uint16_t)(p2 >> 16));
            a0 += bf2f((uint16_t)(p3 & 0xffff)); a1 += bf2f((uint16_t)(p3 >> 16));
        }
        for (; j < cnt; j++){
            int s = __shfl(my, j);
            uint32_t p = tp[(size_t)s*64 + lane];
            a0 += bf2f((uint16_t)(p & 0xffff));
            a1 += bf2f((uint16_t)(p >> 16));
        }
    }
    float isq = rsqrtf((float)max(e1 - e0, 1));
    float r0 = fmaxf(a0*isq + bias[lane*2],   0.f);
    float r1 = fmaxf(a1*isq + bias[lane*2+1], 0.f);
    uint32_t o = (uint32_t)f2bf(r0) | ((uint32_t)f2bf(r1) << 16);
    *(uint32_t*)(hout + (size_t)node*FD + lane*2) = o;
}

// ---- per-graph feature sums. 64 nodes/block; wave reads one 256B row per
// step (lane = feature pair); 16 independent iterations -> deep MLP of loads.
__global__ __launch_bounds__(256) void k_pool(const uint16_t* __restrict__ h,
        const int* __restrict__ n2g, int N, float* __restrict__ pool){
    __shared__ float sacc[NG*FD];
    int t = threadIdx.x;
    for (int i = t; i < NG*FD; i += 256) sacc[i] = 0.f;
    __syncthreads();
    int fp = t & 63;           // feature pair (features 2fp, 2fp+1)
    int no = t >> 6;           // node offset within group of 4
    const uint32_t* hp = (const uint32_t*)h;
    float r0 = 0.f, r1 = 0.f; int rg = -1;
    int base = blockIdx.x * 64;
    #pragma unroll
    for (int i = 0; i < 16; i++){
        int node = base + i*4 + no;
        if (node < N){
            int g = n2g[node];
            if (g != rg){
                if (rg >= 0){
                    atomicAdd(&sacc[rg*FD + fp*2],     r0);
                    atomicAdd(&sacc[rg*FD + fp*2 + 1], r1);
                }
                r0 = r1 = 0.f; rg = g;
            }
            uint32_t p = hp[(size_t)node*64 + fp];
            r0 += bf2f((uint16_t)(p & 0xffff));
            r1 += bf2f((uint16_t)(p >> 16));
        }
    }
    if (rg >= 0){
        atomicAdd(&sacc[rg*FD + fp*2],     r0);
        atomicAdd(&sacc[rg*FD + fp*2 + 1], r1);
    }
    __syncthreads();
    for (int i = t; i < NG*FD; i += 256){
        float v = sacc[i];
        if (v != 0.f) atomicAdd(&pool[i], v);
    }
}

// ---- mean, linear, softmax -> 80 f32 ----
__global__ __launch_bounds__(128) void k_final(const float* __restrict__ pool,
        const int* __restrict__ n2g, int N, const float* __restrict__ Wl,
        const float* __restrict__ bl, float* __restrict__ out){
    __shared__ int ub[NG+1];
    __shared__ float logits[NG][NC];
    int t = threadIdx.x;
    if (t <= NG){
        int lo = 0, hi = N;                 // first i with n2g[i] >= t
        while (lo < hi){ int mid = (lo+hi)>>1; if (n2g[mid] < t) lo = mid+1; else hi = mid; }
        ub[t] = lo;
    }
    __syncthreads();
    if (t < NG*NC){
        int g = t/NC, c = t%NC;
        float cnt = (float)max(ub[g+1]-ub[g], 1);
        float inv = 1.f/cnt;
        float acc = bl[c];
        for (int d=0; d<FD; d++)
            acc += pool[g*FD+d]*inv * Wl[d*NC+c];
        logits[g][c] = acc;
    }
    __syncthreads();
    if (t < NG*NC){
        int g = t/NC, c = t%NC;
        float m = -1e30f;
        for (int i=0;i<NC;i++) m = fmaxf(m, logits[g][i]);
        float ssum = 0.f;
        for (int i=0;i<NC;i++) ssum += expf(logits[g][i]-m);
        out[t] = expf(logits[g][c]-m)/ssum;
    }
}

extern "C" void kernel_launch(void* const* d_in, const int* in_sizes, int n_in,
                              void* d_out, int out_size, void* d_ws, size_t ws_size,
                              hipStream_t stream) {
    const float* x   = (const float*)d_in[0];
    const int*   ei  = (const int*)d_in[1];
    const int*   n2g = (const int*)d_in[2];
    const float* W1  = (const float*)d_in[3];
    const float* b1  = (const float*)d_in[4];
    const float* W2  = (const float*)d_in[5];
    const float* b2  = (const float*)d_in[6];
    const float* Wl  = (const float*)d_in[7];
    const float* bl  = (const float*)d_in[8];
    float* outp = (float*)d_out;

    int N = in_sizes[2];
    int E = in_sizes[1] / 2;

    char* w = (char*)d_ws;
    size_t off = 0;
    auto alloc = [&](size_t bytes)->char*{ char* p = w + off; off += (bytes + 255) & ~(size_t)255; return p; };
    int*      deg_out = (int*)alloc((size_t)N*4);
    int*      deg_in  = (int*)alloc((size_t)N*4);
    int*      cursor  = (int*)alloc((size_t)N*4);
    float*    pool    = (float*)alloc((size_t)NG*FD*4);
    size_t zbytes = off;                         // zeroed region
    int*      bsum    = (int*)alloc(256*4);
    int*      boff    = (int*)alloc(256*4);
    int*      row_off = (int*)alloc((size_t)(N+1)*4);
    int*      csr     = (int*)alloc((size_t)E*4);
    uint16_t* WfHi1   = (uint16_t*)alloc(16384*2);
    uint16_t* WfLo1   = (uint16_t*)alloc(16384*2);
    uint16_t* WfHi2   = (uint16_t*)alloc(16384*2);
    uint16_t* WfLo2   = (uint16_t*)alloc(16384*2);
    uint16_t* tmp     = (uint16_t*)alloc((size_t)N*FD*2);
    uint16_t* hb      = (uint16_t*)alloc((size_t)N*FD*2);
    (void)ws_size;

    hipMemsetAsync(d_ws, 0, zbytes, stream);

    int eb = (E + 255)/256;
    int nb = (N + 255)/256;
    k_prep_w    <<<128, 256, 0, stream>>>(W1, W2, WfHi1, WfLo1, WfHi2, WfLo2);
    k_degree    <<<eb, 256, 0, stream>>>(ei, E, deg_out, deg_in);
    k_bsum      <<<nb, 256, 0, stream>>>(deg_in, N, bsum);
    k_scan_bsum <<<1,  256, 0, stream>>>(bsum, nb, boff, row_off, N, E);
    k_scan_write<<<nb, 256, 0, stream>>>(deg_in, N, boff, row_off);
    k_fill      <<<eb, 256, 0, stream>>>(ei, E, row_off, cursor, csr);

    int gb = (N + 63)/64;
    int sb = (N + 3)/4;
    int pb = (N + 63)/64;
    k_gemm <<<gb, 256, 0, stream>>>(x,  WfHi1, WfLo1, deg_out, tmp, N, 0);
    k_spmm <<<sb, 256, 0, stream>>>(tmp, row_off, csr, b1, hb, N);
    k_gemm <<<gb, 256, 0, stream>>>(hb, WfHi2, WfLo2, deg_out, tmp, N, 1);
    k_spmm <<<sb, 256, 0, stream>>>(tmp, row_off, csr, b2, hb, N);
    k_pool <<<pb, 256, 0, stream>>>(hb, n2g, N, pool);
    k_final<<<1,  128, 0, stream>>>(pool, n2g, N, Wl, bl, outp);
}

// Round 5
// 283.716 us; speedup vs baseline: 1.5428x; 1.1396x over previous
//
#include <hip/hip_runtime.h>
#include <stdint.h>

#define FD 128   // feature dim
#define NG 8     // graphs
#define NC 10    // classes
#define MAXB 1024           // max buckets / max nodes per bucket
#define CHUNK 1024          // edges per counting chunk

typedef __attribute__((ext_vector_type(8))) short bf16x8;
typedef __attribute__((ext_vector_type(4))) float f32x4;

__device__ __forceinline__ float bf2f(uint16_t u){
    union { uint32_t i; float f; } v; v.i = ((uint32_t)u) << 16; return v.f;
}
__device__ __forceinline__ uint16_t f2bf(float f){
    union { float f; uint32_t i; } v; v.f = f;
    uint32_t r = v.i + 0x7fff + ((v.i >> 16) & 1);   // round-to-nearest-even
    return (uint16_t)(r >> 16);
}

// ---- split W1/W2 (f32) into bf16 hi/lo, laid out in MFMA B-fragment order ----
__global__ void k_prep_w(const float* __restrict__ W1, const float* __restrict__ W2,
                         uint16_t* WfHi1, uint16_t* WfLo1, uint16_t* WfHi2, uint16_t* WfLo2){
    int id = blockIdx.x*256 + threadIdx.x;     // 0..32767
    int w = id >> 14;
    int r = id & 16383;
    int j = r & 7, frag = r >> 3;
    int lane = frag & 63, t2 = frag >> 6;
    int n = t2 & 7, kk = t2 >> 3;
    int k = kk*32 + (lane>>4)*8 + j;
    int col = n*16 + (lane&15);
    float v = (w ? W2 : W1)[k*128 + col];
    uint16_t hi = f2bf(v);
    uint16_t lo = f2bf(v - bf2f(hi));
    (w ? WfHi2 : WfHi1)[r] = hi;
    (w ? WfLo2 : WfLo1)[r] = lo;
}

// ============ CSR build via counting sort (no global atomics) ============

// Pass 1: per-chunk bucket histograms for dst (first half) and src (second half).
__global__ __launch_bounds__(256) void k_count(const int* __restrict__ ei, int E,
        int B, int C, int shift, int* __restrict__ cnt){
    __shared__ int hd[MAXB], hs[MAXB];
    int t = threadIdx.x, c = blockIdx.x;
    for (int i=t;i<B;i+=256){ hd[i]=0; hs[i]=0; }
    __syncthreads();
    int e0 = c*CHUNK, e1 = min(E, e0+CHUNK);
    for (int e = e0+t; e < e1; e += 256){
        int s = ei[e], d = ei[E+e];
        atomicAdd(&hd[d>>shift], 1);
        atomicAdd(&hs[s>>shift], 1);
    }
    __syncthreads();
    for (int i=t;i<B;i+=256){
        cnt[(size_t)i*C + c]     = hd[i];
        cnt[(size_t)(B+i)*C + c] = hs[i];
    }
}

// Generic exclusive scan (in-place), 3 kernels. Tile = 256 thr * 16 ept = 4096.
#define SEPT 16
#define STILE 4096
__global__ __launch_bounds__(256) void k_scanA(int* __restrict__ a, int M, int* __restrict__ blksum){
    __shared__ int s[256];
    int t = threadIdx.x;
    int base = blockIdx.x*STILE + t*SEPT;
    int v[SEPT]; int sum = 0;
    #pragma unroll
    for (int i=0;i<SEPT;i++){ int idx=base+i; int x=(idx<M)?a[idx]:0; v[i]=sum; sum+=x; }
    s[t]=sum; __syncthreads();
    for (int o=1;o<256;o<<=1){ int x=(t>=o)?s[t-o]:0; __syncthreads(); s[t]+=x; __syncthreads(); }
    int te = s[t]-sum;
    #pragma unroll
    for (int i=0;i<SEPT;i++){ int idx=base+i; if (idx<M) a[idx]=te+v[i]; }
    if (t==255) blksum[blockIdx.x]=s[t];
}
__global__ __launch_bounds__(256) void k_scanB(int* __restrict__ blksum, int nb){
    __shared__ int s[256];
    int t = threadIdx.x;
    int v[4]; int sum = 0;
    #pragma unroll
    for (int i=0;i<4;i++){ int idx=t*4+i; int x=(idx<nb)?blksum[idx]:0; v[i]=sum; sum+=x; }
    s[t]=sum; __syncthreads();
    for (int o=1;o<256;o<<=1){ int x=(t>=o)?s[t-o]:0; __syncthreads(); s[t]+=x; __syncthreads(); }
    int te = s[t]-sum;
    #pragma unroll
    for (int i=0;i<4;i++){ int idx=t*4+i; if (idx<nb) blksum[idx]=te+v[i]; }
}
__global__ __launch_bounds__(256) void k_scanC(int* __restrict__ a, int M, const int* __restrict__ blksum){
    int add = blksum[blockIdx.x];
    int base = blockIdx.x*STILE + threadIdx.x*SEPT;
    #pragma unroll
    for (int i=0;i<SEPT;i++){ int idx=base+i; if (idx<M) a[idx]+=add; }
}

// Pass 3: scatter edges into bucket-grouped temps using LDS cursors.
__global__ __launch_bounds__(256) void k_scatter(const int* __restrict__ ei, int E,
        int B, int C, int shift, const int* __restrict__ scan,
        uint64_t* __restrict__ tempD, int* __restrict__ tempS){
    __shared__ int cd[MAXB], cs[MAXB];
    int t = threadIdx.x, c = blockIdx.x;
    for (int i=t;i<B;i+=256){
        cd[i] = scan[(size_t)i*C + c];
        cs[i] = scan[(size_t)(B+i)*C + c] - E;
    }
    __syncthreads();
    int e0 = c*CHUNK, e1 = min(E, e0+CHUNK);
    for (int e = e0+t; e < e1; e += 256){
        int s = ei[e], d = ei[E+e];
        int p = atomicAdd(&cd[d>>shift], 1);
        tempD[p] = ((uint64_t)(uint32_t)d << 32) | (uint32_t)s;
        int q = atomicAdd(&cs[s>>shift], 1);
        tempS[q] = s;
    }
}

// Pass 4a: per dst-bucket, build row_off + csr.
__global__ __launch_bounds__(256) void k_build(const uint64_t* __restrict__ tempD,
        const int* __restrict__ scan, int B, int C, int shift, int E, int N,
        int* __restrict__ row_off, int* __restrict__ csr){
    __shared__ int cnt[MAXB];
    __shared__ int offl[MAXB+1];
    int b = blockIdx.x, t = threadIdx.x;
    int range = 1<<shift, nb0 = b<<shift;
    int seg0 = scan[(size_t)b*C];
    int seg1 = (b+1<B) ? scan[(size_t)(b+1)*C] : E;
    for (int i=t;i<range;i+=256) cnt[i]=0;
    __syncthreads();
    for (int i=seg0+t; i<seg1; i+=256)
        atomicAdd(&cnt[(int)(tempD[i]>>32) - nb0], 1);
    __syncthreads();
    if (t==0){ int run=0; for (int i=0;i<range;i++){ offl[i]=run; run+=cnt[i]; } offl[range]=run; }
    __syncthreads();
    for (int i=t;i<range;i+=256){
        int node = nb0+i;
        if (node < N) row_off[node] = seg0 + offl[i];
    }
    if (b==B-1 && t==0) row_off[N] = E;
    for (int i=t;i<range;i+=256) cnt[i] = offl[i];   // reuse as cursor
    __syncthreads();
    for (int i=seg0+t; i<seg1; i+=256){
        uint64_t v = tempD[i];
        int nl = (int)(v>>32) - nb0;
        int p = atomicAdd(&cnt[nl], 1);
        csr[seg0 + p] = (int)(uint32_t)v;
    }
}

// Pass 4b: per src-bucket, per-node out-degree counts.
__global__ __launch_bounds__(256) void k_degout(const int* __restrict__ tempS,
        const int* __restrict__ scan, int B, int C, int shift, int E, int N,
        int* __restrict__ deg_out){
    __shared__ int cnt[MAXB];
    int b = blockIdx.x, t = threadIdx.x;
    int range = 1<<shift, nb0 = b<<shift;
    int seg0 = scan[(size_t)(B+b)*C] - E;
    int seg1 = ((b+1<B) ? scan[(size_t)(B+b+1)*C] : 2*E) - E;
    for (int i=t;i<range;i+=256) cnt[i]=0;
    __syncthreads();
    for (int i=seg0+t; i<seg1; i+=256)
        atomicAdd(&cnt[tempS[i] - nb0], 1);
    __syncthreads();
    for (int i=t;i<range;i+=256){
        int node = nb0+i;
        if (node < N) deg_out[node] = cnt[i];
    }
}

// ============ dense / spmm / pool / final (unchanged from R4) ============

__global__ __launch_bounds__(256) void k_gemm(const void* __restrict__ A,
        const uint16_t* __restrict__ WfHi, const uint16_t* __restrict__ WfLo,
        const int* __restrict__ deg_out, uint16_t* __restrict__ out, int nrows,
        int amode){
    int t = threadIdx.x;
    int wave = t>>6, lane = t&63, quad = lane>>4, low = lane&15;

    int rowA  = blockIdx.x*64 + wave*16 + low;
    int rowAc = min(rowA, nrows-1);

    bf16x8 ah[4], al[4];
    if (amode){
        const uint16_t* arow = (const uint16_t*)A + (size_t)rowAc*FD;
        #pragma unroll
        for (int kk=0;kk<4;kk++)
            ah[kk] = *(const bf16x8*)(arow + kk*32 + quad*8);
    } else {
        const float* arow = (const float*)A + (size_t)rowAc*FD;
        #pragma unroll
        for (int kk=0;kk<4;kk++){
            f32x4 f0 = *(const f32x4*)(arow + kk*32 + quad*8);
            f32x4 f1 = *(const f32x4*)(arow + kk*32 + quad*8 + 4);
            #pragma unroll
            for (int j=0;j<4;j++){
                float f = f0[j]; uint16_t h = f2bf(f);
                ah[kk][j] = (short)h; al[kk][j] = (short)f2bf(f - bf2f(h));
            }
            #pragma unroll
            for (int j=0;j<4;j++){
                float f = f1[j]; uint16_t h = f2bf(f);
                ah[kk][j+4] = (short)h; al[kk][j+4] = (short)f2bf(f - bf2f(h));
            }
        }
    }

    f32x4 acc[8];
    #pragma unroll
    for (int n=0;n<8;n++) acc[n] = (f32x4){0.f,0.f,0.f,0.f};

    #pragma unroll
    for (int kk=0;kk<4;kk++){
        #pragma unroll
        for (int n=0;n<8;n++){
            size_t fo = ((size_t)((kk*8+n)*64 + lane))*8;
            bf16x8 bh = *(const bf16x8*)(WfHi + fo);
            bf16x8 bl = *(const bf16x8*)(WfLo + fo);
            acc[n] = __builtin_amdgcn_mfma_f32_16x16x32_bf16(ah[kk], bh, acc[n], 0, 0, 0);
            if (!amode)
                acc[n] = __builtin_amdgcn_mfma_f32_16x16x32_bf16(al[kk], bh, acc[n], 0, 0, 0);
            acc[n] = __builtin_amdgcn_mfma_f32_16x16x32_bf16(ah[kk], bl, acc[n], 0, 0, 0);
        }
    }

    int rbase = blockIdx.x*64 + wave*16 + quad*4;
    float sc[4]; int rok[4];
    #pragma unroll
    for (int r=0;r<4;r++){
        int row = rbase + r;
        rok[r] = row < nrows;
        int dg = rok[r] ? deg_out[row] : 1;
        sc[r] = rsqrtf((float)max(dg,1));
    }
    #pragma unroll
    for (int n=0;n<8;n++){
        int col = n*16 + low;
        #pragma unroll
        for (int r=0;r<4;r++){
            if (rok[r]) out[(size_t)(rbase+r)*FD + col] = f2bf(acc[n][r]*sc[r]);
        }
    }
}

__global__ __launch_bounds__(256) void k_spmm(const uint16_t* __restrict__ tmp,
        const int* __restrict__ row_off, const int* __restrict__ csr_src,
        const float* __restrict__ bias, uint16_t* __restrict__ hout, int N){
    int node = blockIdx.x*4 + (threadIdx.x>>6);
    int lane = threadIdx.x & 63;
    if (node >= N) return;
    int e0 = row_off[node], e1 = row_off[node+1];
    const uint32_t* tp = (const uint32_t*)tmp;
    float a0 = 0.f, a1 = 0.f;
    for (int base = e0; base < e1; base += 64){
        int my = 0;
        if (base + lane < e1) my = csr_src[base + lane];
        int cnt = min(64, e1 - base);
        int j = 0;
        for (; j + 4 <= cnt; j += 4){
            int s0 = __shfl(my, j);
            int s1 = __shfl(my, j+1);
            int s2 = __shfl(my, j+2);
            int s3 = __shfl(my, j+3);
            uint32_t p0 = tp[(size_t)s0*64 + lane];
            uint32_t p1 = tp[(size_t)s1*64 + lane];
            uint32_t p2 = tp[(size_t)s2*64 + lane];
            uint32_t p3 = tp[(size_t)s3*64 + lane];
            a0 += bf2f((uint16_t)(p0 & 0xffff)); a1 += bf2f((uint16_t)(p0 >> 16));
            a0 += bf2f((uint16_t)(p1 & 0xffff)); a1 += bf2f((uint16_t)(p1 >> 16));
            a0 += bf2f((uint16_t)(p2 & 0xffff)); a1 += bf2f((uint16_t)(p2 >> 16));
            a0 += bf2f((uint16_t)(p3 & 0xffff)); a1 += bf2f((uint16_t)(p3 >> 16));
        }
        for (; j < cnt; j++){
            int s = __shfl(my, j);
            uint32_t p = tp[(size_t)s*64 + lane];
            a0 += bf2f((uint16_t)(p & 0xffff));
            a1 += bf2f((uint16_t)(p >> 16));
        }
    }
    float isq = rsqrtf((float)max(e1 - e0, 1));
    float r0 = fmaxf(a0*isq + bias[lane*2],   0.f);
    float r1 = fmaxf(a1*isq + bias[lane*2+1], 0.f);
    uint32_t o = (uint32_t)f2bf(r0) | ((uint32_t)f2bf(r1) << 16);
    *(uint32_t*)(hout + (size_t)node*FD + lane*2) = o;
}

__global__ __launch_bounds__(256) void k_pool(const uint16_t* __restrict__ h,
        const int* __restrict__ n2g, int N, float* __restrict__ pool){
    __shared__ float sacc[NG*FD];
    int t = threadIdx.x;
    for (int i = t; i < NG*FD; i += 256) sacc[i] = 0.f;
    __syncthreads();
    int fp = t & 63;
    int no = t >> 6;
    const uint32_t* hp = (const uint32_t*)h;
    float r0 = 0.f, r1 = 0.f; int rg = -1;
    int base = blockIdx.x * 64;
    #pragma unroll
    for (int i = 0; i < 16; i++){
        int node = base + i*4 + no;
        if (node < N){
            int g = n2g[node];
            if (g != rg){
                if (rg >= 0){
                    atomicAdd(&sacc[rg*FD + fp*2],     r0);
                    atomicAdd(&sacc[rg*FD + fp*2 + 1], r1);
                }
                r0 = r1 = 0.f; rg = g;
            }
            uint32_t p = hp[(size_t)node*64 + fp];
            r0 += bf2f((uint16_t)(p & 0xffff));
            r1 += bf2f((uint16_t)(p >> 16));
        }
    }
    if (rg >= 0){
        atomicAdd(&sacc[rg*FD + fp*2],     r0);
        atomicAdd(&sacc[rg*FD + fp*2 + 1], r1);
    }
    __syncthreads();
    for (int i = t; i < NG*FD; i += 256){
        float v = sacc[i];
        if (v != 0.f) atomicAdd(&pool[i], v);
    }
}

__global__ __launch_bounds__(128) void k_final(const float* __restrict__ pool,
        const int* __restrict__ n2g, int N, const float* __restrict__ Wl,
        const float* __restrict__ bl, float* __restrict__ out){
    __shared__ int ub[NG+1];
    __shared__ float logits[NG][NC];
    int t = threadIdx.x;
    if (t <= NG){
        int lo = 0, hi = N;
        while (lo < hi){ int mid = (lo+hi)>>1; if (n2g[mid] < t) lo = mid+1; else hi = mid; }
        ub[t] = lo;
    }
    __syncthreads();
    if (t < NG*NC){
        int g = t/NC, c = t%NC;
        float cnt = (float)max(ub[g+1]-ub[g], 1);
        float inv = 1.f/cnt;
        float acc = bl[c];
        for (int d=0; d<FD; d++)
            acc += pool[g*FD+d]*inv * Wl[d*NC+c];
        logits[g][c] = acc;
    }
    __syncthreads();
    if (t < NG*NC){
        int g = t/NC, c = t%NC;
        float m = -1e30f;
        for (int i=0;i<NC;i++) m = fmaxf(m, logits[g][i]);
        float ssum = 0.f;
        for (int i=0;i<NC;i++) ssum += expf(logits[g][i]-m);
        out[t] = expf(logits[g][c]-m)/ssum;
    }
}

extern "C" void kernel_launch(void* const* d_in, const int* in_sizes, int n_in,
                              void* d_out, int out_size, void* d_ws, size_t ws_size,
                              hipStream_t stream) {
    const float* x   = (const float*)d_in[0];
    const int*   ei  = (const int*)d_in[1];
    const int*   n2g = (const int*)d_in[2];
    const float* W1  = (const float*)d_in[3];
    const float* b1  = (const float*)d_in[4];
    const float* W2  = (const float*)d_in[5];
    const float* b2  = (const float*)d_in[6];
    const float* Wl  = (const float*)d_in[7];
    const float* bl  = (const float*)d_in[8];
    float* outp = (float*)d_out;

    int N = in_sizes[2];
    int E = in_sizes[1] / 2;

    // bucket geometry
    int shift = 6;
    while ((((N + (1<<shift) - 1) >> shift) > MAXB) && shift < 10) shift++;
    int B = (N + (1<<shift) - 1) >> shift;
    int C = (E + CHUNK - 1) / CHUNK;
    int M = 2*B*C;

    char* w = (char*)d_ws;
    size_t off = 0;
    auto alloc = [&](size_t bytes)->char*{ char* p = w + off; off += (bytes + 255) & ~(size_t)255; return p; };
    float*    pool    = (float*)alloc((size_t)NG*FD*4);
    size_t zbytes = off;                         // zeroed region: pool only
    int*      deg_out = (int*)alloc((size_t)N*4);
    int*      row_off = (int*)alloc((size_t)(N+1)*4);
    int*      csr     = (int*)alloc((size_t)E*4);
    int*      blksum  = (int*)alloc(1024*4);
    uint16_t* WfHi1   = (uint16_t*)alloc(16384*2);
    uint16_t* WfLo1   = (uint16_t*)alloc(16384*2);
    uint16_t* WfHi2   = (uint16_t*)alloc(16384*2);
    uint16_t* WfLo2   = (uint16_t*)alloc(16384*2);
    uint16_t* tmp     = (uint16_t*)alloc((size_t)N*FD*2);
    uint16_t* hb      = (uint16_t*)alloc((size_t)N*FD*2);
    (void)ws_size;
    // aliases: temps live only during CSR build, before tmp/hb are written
    uint64_t* tempD = (uint64_t*)tmp;            // E*8 <= N*FD*2
    int*      tempS = (int*)(tmp + (size_t)E*4); // E*4 more (tmp is uint16: E*4 halfwords = E*8 bytes)
    int*      cnt   = (int*)hb;                  // M*4 <= N*FD*2

    hipMemsetAsync(d_ws, 0, zbytes, stream);

    int nblkA = (M + STILE - 1) / STILE;
    k_prep_w <<<128, 256, 0, stream>>>(W1, W2, WfHi1, WfLo1, WfHi2, WfLo2);
    k_count  <<<C, 256, 0, stream>>>(ei, E, B, C, shift, cnt);
    k_scanA  <<<nblkA, 256, 0, stream>>>(cnt, M, blksum);
    k_scanB  <<<1, 256, 0, stream>>>(blksum, nblkA);
    k_scanC  <<<nblkA, 256, 0, stream>>>(cnt, M, blksum);
    k_scatter<<<C, 256, 0, stream>>>(ei, E, B, C, shift, cnt, tempD, tempS);
    k_build  <<<B, 256, 0, stream>>>(tempD, cnt, B, C, shift, E, N, row_off, csr);
    k_degout <<<B, 256, 0, stream>>>(tempS, cnt, B, C, shift, E, N, deg_out);

    int gb = (N + 63)/64;
    int sb = (N + 3)/4;
    int pb = (N + 63)/64;
    k_gemm <<<gb, 256, 0, stream>>>(x,  WfHi1, WfLo1, deg_out, tmp, N, 0);
    k_spmm <<<sb, 256, 0, stream>>>(tmp, row_off, csr, b1, hb, N);
    k_gemm <<<gb, 256, 0, stream>>>(hb, WfHi2, WfLo2, deg_out, tmp, N, 1);
    k_spmm <<<sb, 256, 0, stream>>>(tmp, row_off, csr, b2, hb, N);
    k_pool <<<pb, 256, 0, stream>>>(hb, n2g, N, pool);
    k_final<<<1,  128, 0, stream>>>(pool, n2g, N, Wl, bl, outp);
}

// Round 6
// 275.957 us; speedup vs baseline: 1.5862x; 1.0281x over previous
//
#include <hip/hip_runtime.h>
#include <stdint.h>

#define FD 128   // feature dim
#define NG 8     // graphs
#define NC 10    // classes
#define MAXB 1024           // max buckets / max nodes per bucket
#define CHUNK 1024          // edges per counting chunk

typedef __attribute__((ext_vector_type(8))) short bf16x8;
typedef __attribute__((ext_vector_type(4))) float f32x4;

__device__ __forceinline__ float bf2f(uint16_t u){
    union { uint32_t i; float f; } v; v.i = ((uint32_t)u) << 16; return v.f;
}
__device__ __forceinline__ uint16_t f2bf(float f){
    union { float f; uint32_t i; } v; v.f = f;
    uint32_t r = v.i + 0x7fff + ((v.i >> 16) & 1);   // round-to-nearest-even
    return (uint16_t)(r >> 16);
}

// ---- split W1/W2 (f32) into bf16 hi/lo in MFMA fragment order ----
// Wf[((kk*8+n)*64+lane)*8+j] = W[k][col], k=kk*32+(lane>>4)*8+j, col=n*16+(lane&15)
__global__ void k_prep_w(const float* __restrict__ W1, const float* __restrict__ W2,
                         uint16_t* WfHi1, uint16_t* WfLo1, uint16_t* WfHi2, uint16_t* WfLo2){
    int id = blockIdx.x*256 + threadIdx.x;     // 0..32767
    int w = id >> 14;
    int r = id & 16383;
    int j = r & 7, frag = r >> 3;
    int lane = frag & 63, t2 = frag >> 6;
    int n = t2 & 7, kk = t2 >> 3;
    int k = kk*32 + (lane>>4)*8 + j;
    int col = n*16 + (lane&15);
    float v = (w ? W2 : W1)[k*128 + col];
    uint16_t hi = f2bf(v);
    uint16_t lo = f2bf(v - bf2f(hi));
    (w ? WfHi2 : WfHi1)[r] = hi;
    (w ? WfLo2 : WfLo1)[r] = lo;
}

// ============ CSR build via counting sort (no global atomics) ============

__global__ __launch_bounds__(256) void k_count(const int* __restrict__ ei, int E,
        int B, int C, int shift, int* __restrict__ cnt){
    __shared__ int hd[MAXB], hs[MAXB];
    int t = threadIdx.x, c = blockIdx.x;
    for (int i=t;i<B;i+=256){ hd[i]=0; hs[i]=0; }
    __syncthreads();
    int e0 = c*CHUNK, e1 = min(E, e0+CHUNK);
    for (int e = e0+t; e < e1; e += 256){
        int s = ei[e], d = ei[E+e];
        atomicAdd(&hd[d>>shift], 1);
        atomicAdd(&hs[s>>shift], 1);
    }
    __syncthreads();
    for (int i=t;i<B;i+=256){
        cnt[(size_t)i*C + c]     = hd[i];
        cnt[(size_t)(B+i)*C + c] = hs[i];
    }
}

#define SEPT 16
#define STILE 4096
__global__ __launch_bounds__(256) void k_scanA(int* __restrict__ a, int M, int* __restrict__ blksum){
    __shared__ int s[256];
    int t = threadIdx.x;
    int base = blockIdx.x*STILE + t*SEPT;
    int v[SEPT]; int sum = 0;
    #pragma unroll
    for (int i=0;i<SEPT;i++){ int idx=base+i; int x=(idx<M)?a[idx]:0; v[i]=sum; sum+=x; }
    s[t]=sum; __syncthreads();
    for (int o=1;o<256;o<<=1){ int x=(t>=o)?s[t-o]:0; __syncthreads(); s[t]+=x; __syncthreads(); }
    int te = s[t]-sum;
    #pragma unroll
    for (int i=0;i<SEPT;i++){ int idx=base+i; if (idx<M) a[idx]=te+v[i]; }
    if (t==255) blksum[blockIdx.x]=s[t];
}
__global__ __launch_bounds__(256) void k_scanB(int* __restrict__ blksum, int nb){
    __shared__ int s[256];
    int t = threadIdx.x;
    int v[4]; int sum = 0;
    #pragma unroll
    for (int i=0;i<4;i++){ int idx=t*4+i; int x=(idx<nb)?blksum[idx]:0; v[i]=sum; sum+=x; }
    s[t]=sum; __syncthreads();
    for (int o=1;o<256;o<<=1){ int x=(t>=o)?s[t-o]:0; __syncthreads(); s[t]+=x; __syncthreads(); }
    int te = s[t]-sum;
    #pragma unroll
    for (int i=0;i<4;i++){ int idx=t*4+i; if (idx<nb) blksum[idx]=te+v[i]; }
}
__global__ __launch_bounds__(256) void k_scanC(int* __restrict__ a, int M, const int* __restrict__ blksum){
    int add = blksum[blockIdx.x];
    int base = blockIdx.x*STILE + threadIdx.x*SEPT;
    #pragma unroll
    for (int i=0;i<SEPT;i++){ int idx=base+i; if (idx<M) a[idx]+=add; }
}

__global__ __launch_bounds__(256) void k_scatter(const int* __restrict__ ei, int E,
        int B, int C, int shift, const int* __restrict__ scan,
        uint64_t* __restrict__ tempD, int* __restrict__ tempS){
    __shared__ int cd[MAXB], cs[MAXB];
    int t = threadIdx.x, c = blockIdx.x;
    for (int i=t;i<B;i+=256){
        cd[i] = scan[(size_t)i*C + c];
        cs[i] = scan[(size_t)(B+i)*C + c] - E;
    }
    __syncthreads();
    int e0 = c*CHUNK, e1 = min(E, e0+CHUNK);
    for (int e = e0+t; e < e1; e += 256){
        int s = ei[e], d = ei[E+e];
        int p = atomicAdd(&cd[d>>shift], 1);
        tempD[p] = ((uint64_t)(uint32_t)d << 32) | (uint32_t)s;
        int q = atomicAdd(&cs[s>>shift], 1);
        tempS[q] = s;
    }
}

__global__ __launch_bounds__(256) void k_build(const uint64_t* __restrict__ tempD,
        const int* __restrict__ scan, int B, int C, int shift, int E, int N,
        int* __restrict__ row_off, int* __restrict__ csr){
    __shared__ int cnt[MAXB];
    __shared__ int offl[MAXB+1];
    int b = blockIdx.x, t = threadIdx.x;
    int range = 1<<shift, nb0 = b<<shift;
    int seg0 = scan[(size_t)b*C];
    int seg1 = (b+1<B) ? scan[(size_t)(b+1)*C] : E;
    for (int i=t;i<range;i+=256) cnt[i]=0;
    __syncthreads();
    for (int i=seg0+t; i<seg1; i+=256)
        atomicAdd(&cnt[(int)(tempD[i]>>32) - nb0], 1);
    __syncthreads();
    if (t==0){ int run=0; for (int i=0;i<range;i++){ offl[i]=run; run+=cnt[i]; } offl[range]=run; }
    __syncthreads();
    for (int i=t;i<range;i+=256){
        int node = nb0+i;
        if (node < N) row_off[node] = seg0 + offl[i];
    }
    if (b==B-1 && t==0) row_off[N] = E;
    for (int i=t;i<range;i+=256) cnt[i] = offl[i];
    __syncthreads();
    for (int i=seg0+t; i<seg1; i+=256){
        uint64_t v = tempD[i];
        int nl = (int)(v>>32) - nb0;
        int p = atomicAdd(&cnt[nl], 1);
        csr[seg0 + p] = (int)(uint32_t)v;
    }
}

__global__ __launch_bounds__(256) void k_degout(const int* __restrict__ tempS,
        const int* __restrict__ scan, int B, int C, int shift, int E, int N,
        int* __restrict__ deg_out){
    __shared__ int cnt[MAXB];
    int b = blockIdx.x, t = threadIdx.x;
    int range = 1<<shift, nb0 = b<<shift;
    int seg0 = scan[(size_t)(B+b)*C] - E;
    int seg1 = ((b+1<B) ? scan[(size_t)(B+b+1)*C] : 2*E) - E;
    for (int i=t;i<range;i+=256) cnt[i]=0;
    __syncthreads();
    for (int i=seg0+t; i<seg1; i+=256)
        atomicAdd(&cnt[tempS[i] - nb0], 1);
    __syncthreads();
    for (int i=t;i<range;i+=256){
        int node = nb0+i;
        if (node < N) deg_out[node] = cnt[i];
    }
}

// ============ GEMM (swapped-operand MFMA: D = Wfrag x Xfrag) ============
// D[c][xrow]: lane holds xrow = base+low (uniform scale) and 4 consecutive
// cols (quad*4+reg) per acc tile -> 8B packed stores.
__global__ __launch_bounds__(256) void k_gemm(const void* __restrict__ A,
        const uint16_t* __restrict__ WfHi, const uint16_t* __restrict__ WfLo,
        const int* __restrict__ deg_out, uint16_t* __restrict__ out, int nrows,
        int amode){
    int t = threadIdx.x;
    int wave = t>>6, lane = t&63, quad = lane>>4, low = lane&15;

    int rowA  = blockIdx.x*64 + wave*16 + low;
    int rowAc = min(rowA, nrows-1);

    bf16x8 ah[4], al[4];
    if (amode){
        const uint16_t* arow = (const uint16_t*)A + (size_t)rowAc*FD;
        #pragma unroll
        for (int kk=0;kk<4;kk++)
            ah[kk] = *(const bf16x8*)(arow + kk*32 + quad*8);
    } else {
        const float* arow = (const float*)A + (size_t)rowAc*FD;
        #pragma unroll
        for (int kk=0;kk<4;kk++){
            f32x4 f0 = *(const f32x4*)(arow + kk*32 + quad*8);
            f32x4 f1 = *(const f32x4*)(arow + kk*32 + quad*8 + 4);
            #pragma unroll
            for (int j=0;j<4;j++){
                float f = f0[j]; uint16_t h = f2bf(f);
                ah[kk][j] = (short)h; al[kk][j] = (short)f2bf(f - bf2f(h));
            }
            #pragma unroll
            for (int j=0;j<4;j++){
                float f = f1[j]; uint16_t h = f2bf(f);
                ah[kk][j+4] = (short)h; al[kk][j+4] = (short)f2bf(f - bf2f(h));
            }
        }
    }

    f32x4 acc[8];
    #pragma unroll
    for (int n=0;n<8;n++) acc[n] = (f32x4){0.f,0.f,0.f,0.f};

    #pragma unroll
    for (int kk=0;kk<4;kk++){
        #pragma unroll
        for (int n=0;n<8;n++){
            size_t fo = ((size_t)((kk*8+n)*64 + lane))*8;
            bf16x8 bh = *(const bf16x8*)(WfHi + fo);
            bf16x8 bl = *(const bf16x8*)(WfLo + fo);
            // swapped operands: W fragment first -> D[c][xrow]
            acc[n] = __builtin_amdgcn_mfma_f32_16x16x32_bf16(bh, ah[kk], acc[n], 0, 0, 0);
            if (!amode)
                acc[n] = __builtin_amdgcn_mfma_f32_16x16x32_bf16(bh, al[kk], acc[n], 0, 0, 0);
            acc[n] = __builtin_amdgcn_mfma_f32_16x16x32_bf16(bl, ah[kk], acc[n], 0, 0, 0);
        }
    }

    if (rowA < nrows){
        float sc = rsqrtf((float)max(deg_out[rowA], 1));
        uint16_t* orow = out + (size_t)rowA*FD;
        #pragma unroll
        for (int n=0;n<8;n++){
            uint2 pk;
            pk.x = (uint32_t)f2bf(acc[n][0]*sc) | ((uint32_t)f2bf(acc[n][1]*sc) << 16);
            pk.y = (uint32_t)f2bf(acc[n][2]*sc) | ((uint32_t)f2bf(acc[n][3]*sc) << 16);
            *(uint2*)(orow + n*16 + quad*4) = pk;
        }
    }
}

// ============ SpMM: half-wave per node, lane owns 8B (4 feats) ============
__global__ __launch_bounds__(256) void k_spmm(const uint16_t* __restrict__ tmp,
        const int* __restrict__ row_off, const int* __restrict__ csr_src,
        const float* __restrict__ bias, uint16_t* __restrict__ hout, int N){
    int tid = threadIdx.x;
    int node = blockIdx.x*8 + (tid>>5);
    int l  = tid & 31;           // lane within half-wave
    int lb = tid & 32;           // shfl base of this half within the 64-wave
    if (node >= N) return;
    int e0 = row_off[node], e1 = row_off[node+1];
    const uint32_t* tp = (const uint32_t*)tmp;
    float a0=0.f, a1=0.f, a2=0.f, a3=0.f;
    for (int base = e0; base < e1; base += 32){
        int my = 0;
        if (base + l < e1) my = csr_src[base + l];
        int cnt = min(32, e1 - base);
        int j = 0;
        for (; j + 4 <= cnt; j += 4){
            int s0 = __shfl(my, lb+j);
            int s1 = __shfl(my, lb+j+1);
            int s2 = __shfl(my, lb+j+2);
            int s3 = __shfl(my, lb+j+3);
            uint2 p0 = *(const uint2*)(tp + (size_t)s0*64 + l*2);
            uint2 p1 = *(const uint2*)(tp + (size_t)s1*64 + l*2);
            uint2 p2 = *(const uint2*)(tp + (size_t)s2*64 + l*2);
            uint2 p3 = *(const uint2*)(tp + (size_t)s3*64 + l*2);
            a0 += bf2f((uint16_t)(p0.x&0xffff)); a1 += bf2f((uint16_t)(p0.x>>16));
            a2 += bf2f((uint16_t)(p0.y&0xffff)); a3 += bf2f((uint16_t)(p0.y>>16));
            a0 += bf2f((uint16_t)(p1.x&0xffff)); a1 += bf2f((uint16_t)(p1.x>>16));
            a2 += bf2f((uint16_t)(p1.y&0xffff)); a3 += bf2f((uint16_t)(p1.y>>16));
            a0 += bf2f((uint16_t)(p2.x&0xffff)); a1 += bf2f((uint16_t)(p2.x>>16));
            a2 += bf2f((uint16_t)(p2.y&0xffff)); a3 += bf2f((uint16_t)(p2.y>>16));
            a0 += bf2f((uint16_t)(p3.x&0xffff)); a1 += bf2f((uint16_t)(p3.x>>16));
            a2 += bf2f((uint16_t)(p3.y&0xffff)); a3 += bf2f((uint16_t)(p3.y>>16));
        }
        for (; j < cnt; j++){
            int s = __shfl(my, lb+j);
            uint2 p = *(const uint2*)(tp + (size_t)s*64 + l*2);
            a0 += bf2f((uint16_t)(p.x&0xffff)); a1 += bf2f((uint16_t)(p.x>>16));
            a2 += bf2f((uint16_t)(p.y&0xffff)); a3 += bf2f((uint16_t)(p.y>>16));
        }
    }
    float isq = rsqrtf((float)max(e1 - e0, 1));
    f32x4 bs = *(const f32x4*)(bias + l*4);
    float r0 = fmaxf(a0*isq + bs[0], 0.f);
    float r1 = fmaxf(a1*isq + bs[1], 0.f);
    float r2 = fmaxf(a2*isq + bs[2], 0.f);
    float r3 = fmaxf(a3*isq + bs[3], 0.f);
    uint2 o;
    o.x = (uint32_t)f2bf(r0) | ((uint32_t)f2bf(r1) << 16);
    o.y = (uint32_t)f2bf(r2) | ((uint32_t)f2bf(r3) << 16);
    *(uint2*)(hout + (size_t)node*FD + l*4) = o;
}

// ============ pool / final ============
__global__ __launch_bounds__(256) void k_pool(const uint16_t* __restrict__ h,
        const int* __restrict__ n2g, int N, float* __restrict__ pool){
    __shared__ float sacc[NG*FD];
    int t = threadIdx.x;
    for (int i = t; i < NG*FD; i += 256) sacc[i] = 0.f;
    __syncthreads();
    int fp = t & 63;
    int no = t >> 6;
    const uint32_t* hp = (const uint32_t*)h;
    float r0 = 0.f, r1 = 0.f; int rg = -1;
    int base = blockIdx.x * 64;
    #pragma unroll
    for (int i = 0; i < 16; i++){
        int node = base + i*4 + no;
        if (node < N){
            int g = n2g[node];
            if (g != rg){
                if (rg >= 0){
                    atomicAdd(&sacc[rg*FD + fp*2],     r0);
                    atomicAdd(&sacc[rg*FD + fp*2 + 1], r1);
                }
                r0 = r1 = 0.f; rg = g;
            }
            uint32_t p = hp[(size_t)node*64 + fp];
            r0 += bf2f((uint16_t)(p & 0xffff));
            r1 += bf2f((uint16_t)(p >> 16));
        }
    }
    if (rg >= 0){
        atomicAdd(&sacc[rg*FD + fp*2],     r0);
        atomicAdd(&sacc[rg*FD + fp*2 + 1], r1);
    }
    __syncthreads();
    for (int i = t; i < NG*FD; i += 256){
        float v = sacc[i];
        if (v != 0.f) atomicAdd(&pool[i], v);
    }
}

__global__ __launch_bounds__(128) void k_final(const float* __restrict__ pool,
        const int* __restrict__ n2g, int N, const float* __restrict__ Wl,
        const float* __restrict__ bl, float* __restrict__ out){
    __shared__ int ub[NG+1];
    __shared__ float logits[NG][NC];
    int t = threadIdx.x;
    if (t <= NG){
        int lo = 0, hi = N;
        while (lo < hi){ int mid = (lo+hi)>>1; if (n2g[mid] < t) lo = mid+1; else hi = mid; }
        ub[t] = lo;
    }
    __syncthreads();
    if (t < NG*NC){
        int g = t/NC, c = t%NC;
        float cnt = (float)max(ub[g+1]-ub[g], 1);
        float inv = 1.f/cnt;
        float acc = bl[c];
        for (int d=0; d<FD; d++)
            acc += pool[g*FD+d]*inv * Wl[d*NC+c];
        logits[g][c] = acc;
    }
    __syncthreads();
    if (t < NG*NC){
        int g = t/NC, c = t%NC;
        float m = -1e30f;
        for (int i=0;i<NC;i++) m = fmaxf(m, logits[g][i]);
        float ssum = 0.f;
        for (int i=0;i<NC;i++) ssum += expf(logits[g][i]-m);
        out[t] = expf(logits[g][c]-m)/ssum;
    }
}

extern "C" void kernel_launch(void* const* d_in, const int* in_sizes, int n_in,
                              void* d_out, int out_size, void* d_ws, size_t ws_size,
                              hipStream_t stream) {
    const float* x   = (const float*)d_in[0];
    const int*   ei  = (const int*)d_in[1];
    const int*   n2g = (const int*)d_in[2];
    const float* W1  = (const float*)d_in[3];
    const float* b1  = (const float*)d_in[4];
    const float* W2  = (const float*)d_in[5];
    const float* b2  = (const float*)d_in[6];
    const float* Wl  = (const float*)d_in[7];
    const float* bl  = (const float*)d_in[8];
    float* outp = (float*)d_out;

    int N = in_sizes[2];
    int E = in_sizes[1] / 2;

    int shift = 6;
    while ((((N + (1<<shift) - 1) >> shift) > MAXB) && shift < 10) shift++;
    int B = (N + (1<<shift) - 1) >> shift;
    int C = (E + CHUNK - 1) / CHUNK;
    int M = 2*B*C;

    char* w = (char*)d_ws;
    size_t off = 0;
    auto alloc = [&](size_t bytes)->char*{ char* p = w + off; off += (bytes + 255) & ~(size_t)255; return p; };
    float*    pool    = (float*)alloc((size_t)NG*FD*4);
    size_t zbytes = off;
    int*      deg_out = (int*)alloc((size_t)N*4);
    int*      row_off = (int*)alloc((size_t)(N+1)*4);
    int*      csr     = (int*)alloc((size_t)E*4);
    int*      blksum  = (int*)alloc(1024*4);
    uint16_t* WfHi1   = (uint16_t*)alloc(16384*2);
    uint16_t* WfLo1   = (uint16_t*)alloc(16384*2);
    uint16_t* WfHi2   = (uint16_t*)alloc(16384*2);
    uint16_t* WfLo2   = (uint16_t*)alloc(16384*2);
    uint16_t* tmp     = (uint16_t*)alloc((size_t)N*FD*2);
    uint16_t* hb      = (uint16_t*)alloc((size_t)N*FD*2);
    (void)ws_size;
    uint64_t* tempD = (uint64_t*)tmp;
    int*      tempS = (int*)(tmp + (size_t)E*4);
    int*      cnt   = (int*)hb;

    hipMemsetAsync(d_ws, 0, zbytes, stream);

    int nblkA = (M + STILE - 1) / STILE;
    k_prep_w <<<128, 256, 0, stream>>>(W1, W2, WfHi1, WfLo1, WfHi2, WfLo2);
    k_count  <<<C, 256, 0, stream>>>(ei, E, B, C, shift, cnt);
    k_scanA  <<<nblkA, 256, 0, stream>>>(cnt, M, blksum);
    k_scanB  <<<1, 256, 0, stream>>>(blksum, nblkA);
    k_scanC  <<<nblkA, 256, 0, stream>>>(cnt, M, blksum);
    k_scatter<<<C, 256, 0, stream>>>(ei, E, B, C, shift, cnt, tempD, tempS);
    k_build  <<<B, 256, 0, stream>>>(tempD, cnt, B, C, shift, E, N, row_off, csr);
    k_degout <<<B, 256, 0, stream>>>(tempS, cnt, B, C, shift, E, N, deg_out);

    int gb = (N + 63)/64;
    int sb = (N + 7)/8;
    int pb = (N + 63)/64;
    k_gemm <<<gb, 256, 0, stream>>>(x,  WfHi1, WfLo1, deg_out, tmp, N, 0);
    k_spmm <<<sb, 256, 0, stream>>>(tmp, row_off, csr, b1, hb, N);
    k_gemm <<<gb, 256, 0, stream>>>(hb, WfHi2, WfLo2, deg_out, tmp, N, 1);
    k_spmm <<<sb, 256, 0, stream>>>(tmp, row_off, csr, b2, hb, N);
    k_pool <<<pb, 256, 0, stream>>>(hb, n2g, N, pool);
    k_final<<<1,  128, 0, stream>>>(pool, n2g, N, Wl, bl, outp);
}

// Round 7
// 275.479 us; speedup vs baseline: 1.5889x; 1.0017x over previous
//
#include <hip/hip_runtime.h>
#include <stdint.h>

#define FD 128   // feature dim
#define NG 8     // graphs
#define NC 10    // classes
#define MAXB 1024           // max buckets / max nodes per bucket
#define CHUNK 1024          // edges per counting chunk

typedef __attribute__((ext_vector_type(8))) short bf16x8;
typedef __attribute__((ext_vector_type(4))) float f32x4;
typedef __attribute__((ext_vector_type(2))) float f32x2;

__device__ __forceinline__ float bf2f(uint16_t u){
    union { uint32_t i; float f; } v; v.i = ((uint32_t)u) << 16; return v.f;
}
__device__ __forceinline__ uint16_t f2bf(float f){
    union { float f; uint32_t i; } v; v.f = f;
    uint32_t r = v.i + 0x7fff + ((v.i >> 16) & 1);   // round-to-nearest-even
    return (uint16_t)(r >> 16);
}
// unpack 2 bf16 (packed in u32) -> (low, high) as f32 pair
__device__ __forceinline__ f32x2 up2(uint32_t p){
    union { uint32_t i; float f; } a, b;
    a.i = p << 16; b.i = p & 0xFFFF0000u;
    return (f32x2){a.f, b.f};
}

// ---- split W1/W2 (f32) into bf16 hi/lo in MFMA fragment order ----
__global__ void k_prep_w(const float* __restrict__ W1, const float* __restrict__ W2,
                         uint16_t* WfHi1, uint16_t* WfLo1, uint16_t* WfHi2, uint16_t* WfLo2){
    int id = blockIdx.x*256 + threadIdx.x;     // 0..32767
    int w = id >> 14;
    int r = id & 16383;
    int j = r & 7, frag = r >> 3;
    int lane = frag & 63, t2 = frag >> 6;
    int n = t2 & 7, kk = t2 >> 3;
    int k = kk*32 + (lane>>4)*8 + j;
    int col = n*16 + (lane&15);
    float v = (w ? W2 : W1)[k*128 + col];
    uint16_t hi = f2bf(v);
    uint16_t lo = f2bf(v - bf2f(hi));
    (w ? WfHi2 : WfHi1)[r] = hi;
    (w ? WfLo2 : WfLo1)[r] = lo;
}

// ============ CSR build via counting sort (no global atomics) ============

// Pass 1: per-chunk histograms, written CHUNK-MAJOR (coalesced): cntT[c][i]
__global__ __launch_bounds__(256) void k_count(const int* __restrict__ ei, int E,
        int B, int C, int shift, int* __restrict__ cntT){
    __shared__ int hd[MAXB], hs[MAXB];
    int t = threadIdx.x, c = blockIdx.x;
    for (int i=t;i<B;i+=256){ hd[i]=0; hs[i]=0; }
    __syncthreads();
    int e0 = c*CHUNK, e1 = min(E, e0+CHUNK);
    for (int e = e0+t; e < e1; e += 256){
        int s = ei[e], d = ei[E+e];
        atomicAdd(&hd[d>>shift], 1);
        atomicAdd(&hs[s>>shift], 1);
    }
    __syncthreads();
    int* row = cntT + (size_t)c*2*B;
    for (int i=t;i<B;i+=256){ row[i] = hd[i]; row[B+i] = hs[i]; }
}

// LDS-tiled transpose: in[r*K + k] -> out[k*R + r]
__global__ __launch_bounds__(256) void k_transpose(const int* __restrict__ in,
        int* __restrict__ out, int R, int K){
    __shared__ int tile[32][33];
    int k0 = blockIdx.x*32, r0 = blockIdx.y*32;
    int tx = threadIdx.x & 31, ty = threadIdx.x >> 5;
    for (int i = ty; i < 32; i += 8){
        int r = r0 + i, k = k0 + tx;
        tile[i][tx] = (r < R && k < K) ? in[(size_t)r*K + k] : 0;
    }
    __syncthreads();
    for (int i = ty; i < 32; i += 8){
        int k = k0 + i, r = r0 + tx;
        if (k < K && r < R) out[(size_t)k*R + r] = tile[tx][i];
    }
}

#define SEPT 16
#define STILE 4096
__global__ __launch_bounds__(256) void k_scanA(int* __restrict__ a, int M, int* __restrict__ blksum){
    __shared__ int s[256];
    int t = threadIdx.x;
    int base = blockIdx.x*STILE + t*SEPT;
    int v[SEPT]; int sum = 0;
    #pragma unroll
    for (int i=0;i<SEPT;i++){ int idx=base+i; int x=(idx<M)?a[idx]:0; v[i]=sum; sum+=x; }
    s[t]=sum; __syncthreads();
    for (int o=1;o<256;o<<=1){ int x=(t>=o)?s[t-o]:0; __syncthreads(); s[t]+=x; __syncthreads(); }
    int te = s[t]-sum;
    #pragma unroll
    for (int i=0;i<SEPT;i++){ int idx=base+i; if (idx<M) a[idx]=te+v[i]; }
    if (t==255) blksum[blockIdx.x]=s[t];
}
__global__ __launch_bounds__(256) void k_scanB(int* __restrict__ blksum, int nb){
    __shared__ int s[256];
    int t = threadIdx.x;
    int v[4]; int sum = 0;
    #pragma unroll
    for (int i=0;i<4;i++){ int idx=t*4+i; int x=(idx<nb)?blksum[idx]:0; v[i]=sum; sum+=x; }
    s[t]=sum; __syncthreads();
    for (int o=1;o<256;o<<=1){ int x=(t>=o)?s[t-o]:0; __syncthreads(); s[t]+=x; __syncthreads(); }
    int te = s[t]-sum;
    #pragma unroll
    for (int i=0;i<4;i++){ int idx=t*4+i; if (idx<nb) blksum[idx]=te+v[i]; }
}
__global__ __launch_bounds__(256) void k_scanC(int* __restrict__ a, int M, const int* __restrict__ blksum){
    int add = blksum[blockIdx.x];
    int base = blockIdx.x*STILE + threadIdx.x*SEPT;
    #pragma unroll
    for (int i=0;i<SEPT;i++){ int idx=base+i; if (idx<M) a[idx]+=add; }
}

// Pass 3: scatter edges; cursors read coalesced from chunk-major scanT.
// tempD packed: (d_local<<20)|src  (needs N < 2^20); tempS: uint16 (N < 65536).
__global__ __launch_bounds__(256) void k_scatter(const int* __restrict__ ei, int E,
        int B, int C, int shift, const int* __restrict__ scanT,
        uint32_t* __restrict__ tempD, uint16_t* __restrict__ tempS){
    __shared__ int cd[MAXB], cs[MAXB];
    int t = threadIdx.x, c = blockIdx.x;
    const int* row = scanT + (size_t)c*2*B;
    for (int i=t;i<B;i+=256){ cd[i] = row[i]; cs[i] = row[B+i] - E; }
    __syncthreads();
    int e0 = c*CHUNK, e1 = min(E, e0+CHUNK);
    int lmask = (1<<shift) - 1;
    for (int e = e0+t; e < e1; e += 256){
        int s = ei[e], d = ei[E+e];
        int p = atomicAdd(&cd[d>>shift], 1);
        tempD[p] = ((uint32_t)(d & lmask) << 20) | (uint32_t)s;
        int q = atomicAdd(&cs[s>>shift], 1);
        tempS[q] = (uint16_t)s;
    }
}

// Pass 4: per bucket, build row_off + csr (dst) and deg_out (src).
__global__ __launch_bounds__(256) void k_build2(const uint32_t* __restrict__ tempD,
        const uint16_t* __restrict__ tempS, const int* __restrict__ scan,
        int B, int C, int shift, int E, int N,
        int* __restrict__ row_off, int* __restrict__ csr, int* __restrict__ deg_out){
    __shared__ int cnt[MAXB];
    __shared__ int offl[MAXB];
    int b = blockIdx.x, t = threadIdx.x;
    int range = 1<<shift, nb0 = b<<shift;
    // dst bucket
    int seg0 = scan[(size_t)b*C];
    int seg1 = (b+1<B) ? scan[(size_t)(b+1)*C] : E;
    for (int i=t;i<range;i+=256) cnt[i]=0;
    __syncthreads();
    for (int i=seg0+t; i<seg1; i+=256)
        atomicAdd(&cnt[tempD[i]>>20], 1);
    __syncthreads();
    if (t==0){ int run=0; for (int i=0;i<range;i++){ offl[i]=run; run+=cnt[i]; } }
    __syncthreads();
    for (int i=t;i<range;i+=256){
        int node = nb0+i;
        if (node < N) row_off[node] = seg0 + offl[i];
    }
    if (b==B-1 && t==0) row_off[N] = E;
    for (int i=t;i<range;i+=256) cnt[i] = offl[i];
    __syncthreads();
    for (int i=seg0+t; i<seg1; i+=256){
        uint32_t v = tempD[i];
        int p = atomicAdd(&cnt[v>>20], 1);
        csr[seg0 + p] = (int)(v & 0xFFFFFu);
    }
    // src bucket -> deg_out
    __syncthreads();
    int sg0 = scan[(size_t)(B+b)*C] - E;
    int sg1 = ((b+1<B) ? scan[(size_t)(B+b+1)*C] : 2*E) - E;
    for (int i=t;i<range;i+=256) cnt[i]=0;
    __syncthreads();
    for (int i=sg0+t; i<sg1; i+=256)
        atomicAdd(&cnt[(int)tempS[i] - nb0], 1);
    __syncthreads();
    for (int i=t;i<range;i+=256){
        int node = nb0+i;
        if (node < N) deg_out[node] = cnt[i];
    }
}

// ============ GEMM (swapped-operand MFMA: D = Wfrag x Xfrag) ============
__global__ __launch_bounds__(256) void k_gemm(const void* __restrict__ A,
        const uint16_t* __restrict__ WfHi, const uint16_t* __restrict__ WfLo,
        const int* __restrict__ deg_out, uint16_t* __restrict__ out, int nrows,
        int amode){
    int t = threadIdx.x;
    int wave = t>>6, lane = t&63, quad = lane>>4, low = lane&15;

    int rowA  = blockIdx.x*64 + wave*16 + low;
    int rowAc = min(rowA, nrows-1);

    bf16x8 ah[4], al[4];
    if (amode){
        const uint16_t* arow = (const uint16_t*)A + (size_t)rowAc*FD;
        #pragma unroll
        for (int kk=0;kk<4;kk++)
            ah[kk] = *(const bf16x8*)(arow + kk*32 + quad*8);
    } else {
        const float* arow = (const float*)A + (size_t)rowAc*FD;
        #pragma unroll
        for (int kk=0;kk<4;kk++){
            f32x4 f0 = *(const f32x4*)(arow + kk*32 + quad*8);
            f32x4 f1 = *(const f32x4*)(arow + kk*32 + quad*8 + 4);
            #pragma unroll
            for (int j=0;j<4;j++){
                float f = f0[j]; uint16_t h = f2bf(f);
                ah[kk][j] = (short)h; al[kk][j] = (short)f2bf(f - bf2f(h));
            }
            #pragma unroll
            for (int j=0;j<4;j++){
                float f = f1[j]; uint16_t h = f2bf(f);
                ah[kk][j+4] = (short)h; al[kk][j+4] = (short)f2bf(f - bf2f(h));
            }
        }
    }

    f32x4 acc[8];
    #pragma unroll
    for (int n=0;n<8;n++) acc[n] = (f32x4){0.f,0.f,0.f,0.f};

    #pragma unroll
    for (int kk=0;kk<4;kk++){
        #pragma unroll
        for (int n=0;n<8;n++){
            size_t fo = ((size_t)((kk*8+n)*64 + lane))*8;
            bf16x8 bh = *(const bf16x8*)(WfHi + fo);
            bf16x8 bl = *(const bf16x8*)(WfLo + fo);
            acc[n] = __builtin_amdgcn_mfma_f32_16x16x32_bf16(bh, ah[kk], acc[n], 0, 0, 0);
            if (!amode)
                acc[n] = __builtin_amdgcn_mfma_f32_16x16x32_bf16(bh, al[kk], acc[n], 0, 0, 0);
            acc[n] = __builtin_amdgcn_mfma_f32_16x16x32_bf16(bl, ah[kk], acc[n], 0, 0, 0);
        }
    }

    if (rowA < nrows){
        float sc = rsqrtf((float)max(deg_out[rowA], 1));
        uint16_t* orow = out + (size_t)rowA*FD;
        #pragma unroll
        for (int n=0;n<8;n++){
            uint2 pk;
            pk.x = (uint32_t)f2bf(acc[n][0]*sc) | ((uint32_t)f2bf(acc[n][1]*sc) << 16);
            pk.y = (uint32_t)f2bf(acc[n][2]*sc) | ((uint32_t)f2bf(acc[n][3]*sc) << 16);
            *(uint2*)(orow + n*16 + quad*4) = pk;
        }
    }
}

// ============ SpMM: full wave per node, 2 edges/iteration (no divergence) ====
// lanes 0-31 process edge j, lanes 32-63 edge j+1; lane owns 8B (4 feats).
__global__ __launch_bounds__(256) void k_spmm(const uint16_t* __restrict__ tmp,
        const int* __restrict__ row_off, const int* __restrict__ csr_src,
        const float* __restrict__ bias, uint16_t* __restrict__ hout, int N){
    int node = blockIdx.x*4 + (threadIdx.x>>6);
    int lane = threadIdx.x & 63;
    int l = lane & 31, half = lane >> 5;
    if (node >= N) return;
    int e0 = row_off[node], e1 = row_off[node+1];
    const uint32_t* tp = (const uint32_t*)tmp;
    f32x2 a01 = {0.f,0.f}, a23 = {0.f,0.f};
    for (int base = e0; base < e1; base += 64){
        int my = 0;
        if (base + lane < e1) my = csr_src[base + lane];
        int cnt = min(64, e1 - base);
        int j = 0;
        for (; j + 8 <= cnt; j += 8){
            int s0 = __shfl(my, j   + half);
            int s1 = __shfl(my, j+2 + half);
            int s2 = __shfl(my, j+4 + half);
            int s3 = __shfl(my, j+6 + half);
            uint2 p0 = *(const uint2*)(tp + (size_t)s0*64 + l*2);
            uint2 p1 = *(const uint2*)(tp + (size_t)s1*64 + l*2);
            uint2 p2 = *(const uint2*)(tp + (size_t)s2*64 + l*2);
            uint2 p3 = *(const uint2*)(tp + (size_t)s3*64 + l*2);
            a01 += up2(p0.x); a23 += up2(p0.y);
            a01 += up2(p1.x); a23 += up2(p1.y);
            a01 += up2(p2.x); a23 += up2(p2.y);
            a01 += up2(p3.x); a23 += up2(p3.y);
        }
        for (; j < cnt; j += 2){
            int idx = j + half;
            int s = __shfl(my, (idx < cnt) ? idx : j);
            uint2 p = *(const uint2*)(tp + (size_t)s*64 + l*2);
            if (idx < cnt){ a01 += up2(p.x); a23 += up2(p.y); }
        }
    }
    // combine the two halves (both halves accumulated same feature columns)
    a01.x += __shfl_xor(a01.x, 32);
    a01.y += __shfl_xor(a01.y, 32);
    a23.x += __shfl_xor(a23.x, 32);
    a23.y += __shfl_xor(a23.y, 32);
    if (half == 0){
        float isq = rsqrtf((float)max(e1 - e0, 1));
        f32x4 bs = *(const f32x4*)(bias + l*4);
        float r0 = fmaxf(a01.x*isq + bs[0], 0.f);
        float r1 = fmaxf(a01.y*isq + bs[1], 0.f);
        float r2 = fmaxf(a23.x*isq + bs[2], 0.f);
        float r3 = fmaxf(a23.y*isq + bs[3], 0.f);
        uint2 o;
        o.x = (uint32_t)f2bf(r0) | ((uint32_t)f2bf(r1) << 16);
        o.y = (uint32_t)f2bf(r2) | ((uint32_t)f2bf(r3) << 16);
        *(uint2*)(hout + (size_t)node*FD + l*4) = o;
    }
}

// ============ pool / final ============
__global__ __launch_bounds__(256) void k_pool(const uint16_t* __restrict__ h,
        const int* __restrict__ n2g, int N, float* __restrict__ pool){
    __shared__ float sacc[NG*FD];
    int t = threadIdx.x;
    for (int i = t; i < NG*FD; i += 256) sacc[i] = 0.f;
    __syncthreads();
    int fp = t & 63;
    int no = t >> 6;
    const uint32_t* hp = (const uint32_t*)h;
    float r0 = 0.f, r1 = 0.f; int rg = -1;
    int base = blockIdx.x * 64;
    #pragma unroll
    for (int i = 0; i < 16; i++){
        int node = base + i*4 + no;
        if (node < N){
            int g = n2g[node];
            if (g != rg){
                if (rg >= 0){
                    atomicAdd(&sacc[rg*FD + fp*2],     r0);
                    atomicAdd(&sacc[rg*FD + fp*2 + 1], r1);
                }
                r0 = r1 = 0.f; rg = g;
            }
            uint32_t p = hp[(size_t)node*64 + fp];
            r0 += bf2f((uint16_t)(p & 0xffff));
            r1 += bf2f((uint16_t)(p >> 16));
        }
    }
    if (rg >= 0){
        atomicAdd(&sacc[rg*FD + fp*2],     r0);
        atomicAdd(&sacc[rg*FD + fp*2 + 1], r1);
    }
    __syncthreads();
    for (int i = t; i < NG*FD; i += 256){
        float v = sacc[i];
        if (v != 0.f) atomicAdd(&pool[i], v);
    }
}

__global__ __launch_bounds__(128) void k_final(const float* __restrict__ pool,
        const int* __restrict__ n2g, int N, const float* __restrict__ Wl,
        const float* __restrict__ bl, float* __restrict__ out){
    __shared__ int ub[NG+1];
    __shared__ float logits[NG][NC];
    int t = threadIdx.x;
    if (t <= NG){
        int lo = 0, hi = N;
        while (lo < hi){ int mid = (lo+hi)>>1; if (n2g[mid] < t) lo = mid+1; else hi = mid; }
        ub[t] = lo;
    }
    __syncthreads();
    if (t < NG*NC){
        int g = t/NC, c = t%NC;
        float cnt = (float)max(ub[g+1]-ub[g], 1);
        float inv = 1.f/cnt;
        float acc = bl[c];
        for (int d=0; d<FD; d++)
            acc += pool[g*FD+d]*inv * Wl[d*NC+c];
        logits[g][c] = acc;
    }
    __syncthreads();
    if (t < NG*NC){
        int g = t/NC, c = t%NC;
        float m = -1e30f;
        for (int i=0;i<NC;i++) m = fmaxf(m, logits[g][i]);
        float ssum = 0.f;
        for (int i=0;i<NC;i++) ssum += expf(logits[g][i]-m);
        out[t] = expf(logits[g][c]-m)/ssum;
    }
}

extern "C" void kernel_launch(void* const* d_in, const int* in_sizes, int n_in,
                              void* d_out, int out_size, void* d_ws, size_t ws_size,
                              hipStream_t stream) {
    const float* x   = (const float*)d_in[0];
    const int*   ei  = (const int*)d_in[1];
    const int*   n2g = (const int*)d_in[2];
    const float* W1  = (const float*)d_in[3];
    const float* b1  = (const float*)d_in[4];
    const float* W2  = (const float*)d_in[5];
    const float* b2  = (const float*)d_in[6];
    const float* Wl  = (const float*)d_in[7];
    const float* bl  = (const float*)d_in[8];
    float* outp = (float*)d_out;

    int N = in_sizes[2];
    int E = in_sizes[1] / 2;

    int shift = 6;
    while ((((N + (1<<shift) - 1) >> shift) > MAXB) && shift < 10) shift++;
    int B = (N + (1<<shift) - 1) >> shift;
    int C = (E + CHUNK - 1) / CHUNK;
    int M = 2*B*C;

    char* w = (char*)d_ws;
    size_t off = 0;
    auto alloc = [&](size_t bytes)->char*{ char* p = w + off; off += (bytes + 255) & ~(size_t)255; return p; };
    float*    pool    = (float*)alloc((size_t)NG*FD*4);
    size_t zbytes = off;
    int*      deg_out = (int*)alloc((size_t)N*4);
    int*      row_off = (int*)alloc((size_t)(N+1)*4);
    int*      csr     = (int*)alloc((size_t)E*4);
    int*      blksum  = (int*)alloc(1024*4);
    uint16_t* WfHi1   = (uint16_t*)alloc(16384*2);
    uint16_t* WfLo1   = (uint16_t*)alloc(16384*2);
    uint16_t* WfHi2   = (uint16_t*)alloc(16384*2);
    uint16_t* WfLo2   = (uint16_t*)alloc(16384*2);
    uint16_t* tmp     = (uint16_t*)alloc((size_t)N*FD*2);
    uint16_t* hb      = (uint16_t*)alloc((size_t)N*FD*2);
    (void)ws_size;
    // aliases (live only during CSR build, before tmp/hb are written)
    uint32_t* tempD = (uint32_t*)tmp;                       // E*4 bytes
    uint16_t* tempS = (uint16_t*)tmp + (size_t)E*2;         // E*2 bytes
    size_t szM = ((size_t)M*4 + 255) & ~(size_t)255;
    int* cntT = (int*)hb;                                   // chunk-major; reused as scanT
    int* cnt  = (int*)((char*)hb + szM);                    // bucket-major (scanned)

    hipMemsetAsync(d_ws, 0, zbytes, stream);

    int nblkA = (M + STILE - 1) / STILE;
    dim3 tg1((2*B + 31)/32, (C + 31)/32);
    dim3 tg2((C + 31)/32, (2*B + 31)/32);
    k_prep_w   <<<128, 256, 0, stream>>>(W1, W2, WfHi1, WfLo1, WfHi2, WfLo2);
    k_count    <<<C, 256, 0, stream>>>(ei, E, B, C, shift, cntT);
    k_transpose<<<tg1, 256, 0, stream>>>(cntT, cnt, C, 2*B);       // -> bucket-major
    k_scanA    <<<nblkA, 256, 0, stream>>>(cnt, M, blksum);
    k_scanB    <<<1, 256, 0, stream>>>(blksum, nblkA);
    k_scanC    <<<nblkA, 256, 0, stream>>>(cnt, M, blksum);
    k_transpose<<<tg2, 256, 0, stream>>>(cnt, cntT, 2*B, C);       // -> chunk-major scanT
    k_scatter  <<<C, 256, 0, stream>>>(ei, E, B, C, shift, cntT, tempD, tempS);
    k_build2   <<<B, 256, 0, stream>>>(tempD, tempS, cnt, B, C, shift, E, N, row_off, csr, deg_out);

    int gb = (N + 63)/64;
    int sb = (N + 3)/4;
    int pb = (N + 63)/64;
    k_gemm <<<gb, 256, 0, stream>>>(x,  WfHi1, WfLo1, deg_out, tmp, N, 0);
    k_spmm <<<sb, 256, 0, stream>>>(tmp, row_off, csr, b1, hb, N);
    k_gemm <<<gb, 256, 0, stream>>>(hb, WfHi2, WfLo2, deg_out, tmp, N, 1);
    k_spmm <<<sb, 256, 0, stream>>>(tmp, row_off, csr, b2, hb, N);
    k_pool <<<pb, 256, 0, stream>>>(hb, n2g, N, pool);
    k_final<<<1,  128, 0, stream>>>(pool, n2g, N, Wl, bl, outp);
}

// Round 8
// 251.570 us; speedup vs baseline: 1.7399x; 1.0950x over previous
//
#include <hip/hip_runtime.h>
#include <stdint.h>

#define FD 128   // feature dim
#define NG 8     // graphs
#define NC 10    // classes
#define MAXB 1024           // max buckets / max nodes per bucket
#define CHUNK 1024          // edges per counting chunk

typedef __attribute__((ext_vector_type(8))) short bf16x8;
typedef __attribute__((ext_vector_type(4))) float f32x4;
typedef __attribute__((ext_vector_type(2))) float f32x2;

__device__ __forceinline__ float bf2f(uint16_t u){
    union { uint32_t i; float f; } v; v.i = ((uint32_t)u) << 16; return v.f;
}
__device__ __forceinline__ uint16_t f2bf(float f){
    union { float f; uint32_t i; } v; v.f = f;
    uint32_t r = v.i + 0x7fff + ((v.i >> 16) & 1);   // round-to-nearest-even
    return (uint16_t)(r >> 16);
}

// ---- fp8 e4m3 conversions (HW path with manual fallback) ----
#if __has_builtin(__builtin_amdgcn_cvt_pk_f32_fp8) && __has_builtin(__builtin_amdgcn_cvt_pk_fp8_f32)
#define FP8_HW 1
__device__ __forceinline__ f32x2 fp8lo2f(uint32_t p){   // bytes 0,1 -> floats
    return __builtin_amdgcn_cvt_pk_f32_fp8((int)p, false);
}
__device__ __forceinline__ f32x2 fp8hi2f(uint32_t p){   // bytes 2,3 -> floats
    return __builtin_amdgcn_cvt_pk_f32_fp8((int)p, true);
}
__device__ __forceinline__ uint32_t pk4fp8(float a, float b, float c, float d){
    int u = 0;
    u = __builtin_amdgcn_cvt_pk_fp8_f32(a, b, u, false);
    u = __builtin_amdgcn_cvt_pk_fp8_f32(c, d, u, true);
    return (uint32_t)u;
}
#else
__device__ __forceinline__ float fp8tof(uint32_t b){    // one e4m3 byte -> f32
    union { uint32_t i; float f; } v;
    v.i = ((b & 0x7f) << 20) | ((b & 0x80) << 24);
    return v.f * 0x1p120f;                              // handles denormals
}
__device__ __forceinline__ f32x2 fp8lo2f(uint32_t p){
    return (f32x2){fp8tof(p & 0xff), fp8tof((p >> 8) & 0xff)};
}
__device__ __forceinline__ f32x2 fp8hi2f(uint32_t p){
    return (f32x2){fp8tof((p >> 16) & 0xff), fp8tof((p >> 24) & 0xff)};
}
__device__ __forceinline__ uint32_t f2fp8(float f){     // f32 -> e4m3 RNE
    union { float f; uint32_t i; } v; v.f = f;
    uint32_t s = (v.i >> 24) & 0x80;
    float a = fabsf(f);
    if (a < 0x1p-10f) return s;                          // flush tiny
    if (a > 448.f) return s | 0x7e;
    v.f = a;
    uint32_t r = v.i + 0x7ffff + ((v.i >> 20) & 1);      // RNE at bit 20
    int e = (int)(r >> 23) - 127 + 7;
    uint32_t m = (r >> 20) & 7;
    if (e <= 0){                                         // denormal: m*2^-9
        uint32_t q = (uint32_t)(a * 512.f + 0.5f);
        return s | (q > 7 ? 8 : q);
    }
    if (e > 15) return s | 0x7e;
    return s | ((uint32_t)e << 3) | m;
}
__device__ __forceinline__ uint32_t pk4fp8(float a, float b, float c, float d){
    return (uint32_t)f2fp8(a) | ((uint32_t)f2fp8(b)<<8) |
           ((uint32_t)f2fp8(c)<<16) | ((uint32_t)f2fp8(d)<<24);
}
#endif

// ---- W1/W2 (f32) -> bf16 in MFMA fragment order ----
// Wf[((kk*8+n)*64+lane)*8+j] = W[k][col], k=kk*32+(lane>>4)*8+j, col=n*16+(lane&15)
__global__ void k_prep_w(const float* __restrict__ W1, const float* __restrict__ W2,
                         uint16_t* Wf1, uint16_t* Wf2){
    int id = blockIdx.x*256 + threadIdx.x;     // 0..32767
    int w = id >> 14;
    int r = id & 16383;
    int j = r & 7, frag = r >> 3;
    int lane = frag & 63, t2 = frag >> 6;
    int n = t2 & 7, kk = t2 >> 3;
    int k = kk*32 + (lane>>4)*8 + j;
    int col = n*16 + (lane&15);
    float v = (w ? W2 : W1)[k*128 + col];
    (w ? Wf2 : Wf1)[r] = f2bf(v);
}

// ============ CSR build via counting sort (no global atomics) ============

__global__ __launch_bounds__(256) void k_count(const int* __restrict__ ei, int E,
        int B, int C, int shift, int* __restrict__ cntT){
    __shared__ int hd[MAXB], hs[MAXB];
    int t = threadIdx.x, c = blockIdx.x;
    for (int i=t;i<B;i+=256){ hd[i]=0; hs[i]=0; }
    __syncthreads();
    int e0 = c*CHUNK, e1 = min(E, e0+CHUNK);
    for (int e = e0+t; e < e1; e += 256){
        int s = ei[e], d = ei[E+e];
        atomicAdd(&hd[d>>shift], 1);
        atomicAdd(&hs[s>>shift], 1);
    }
    __syncthreads();
    int* row = cntT + (size_t)c*2*B;
    for (int i=t;i<B;i+=256){ row[i] = hd[i]; row[B+i] = hs[i]; }
}

__global__ __launch_bounds__(256) void k_transpose(const int* __restrict__ in,
        int* __restrict__ out, int R, int K){
    __shared__ int tile[32][33];
    int k0 = blockIdx.x*32, r0 = blockIdx.y*32;
    int tx = threadIdx.x & 31, ty = threadIdx.x >> 5;
    for (int i = ty; i < 32; i += 8){
        int r = r0 + i, k = k0 + tx;
        tile[i][tx] = (r < R && k < K) ? in[(size_t)r*K + k] : 0;
    }
    __syncthreads();
    for (int i = ty; i < 32; i += 8){
        int k = k0 + i, r = r0 + tx;
        if (k < K && r < R) out[(size_t)k*R + r] = tile[tx][i];
    }
}

#define SEPT 16
#define STILE 4096
__global__ __launch_bounds__(256) void k_scanA(int* __restrict__ a, int M, int* __restrict__ blksum){
    __shared__ int s[256];
    int t = threadIdx.x;
    int base = blockIdx.x*STILE + t*SEPT;
    int v[SEPT]; int sum = 0;
    #pragma unroll
    for (int i=0;i<SEPT;i++){ int idx=base+i; int x=(idx<M)?a[idx]:0; v[i]=sum; sum+=x; }
    s[t]=sum; __syncthreads();
    for (int o=1;o<256;o<<=1){ int x=(t>=o)?s[t-o]:0; __syncthreads(); s[t]+=x; __syncthreads(); }
    int te = s[t]-sum;
    #pragma unroll
    for (int i=0;i<SEPT;i++){ int idx=base+i; if (idx<M) a[idx]=te+v[i]; }
    if (t==255) blksum[blockIdx.x]=s[t];
}
__global__ __launch_bounds__(256) void k_scanB(int* __restrict__ blksum, int nb){
    __shared__ int s[256];
    int t = threadIdx.x;
    int v[4]; int sum = 0;
    #pragma unroll
    for (int i=0;i<4;i++){ int idx=t*4+i; int x=(idx<nb)?blksum[idx]:0; v[i]=sum; sum+=x; }
    s[t]=sum; __syncthreads();
    for (int o=1;o<256;o<<=1){ int x=(t>=o)?s[t-o]:0; __syncthreads(); s[t]+=x; __syncthreads(); }
    int te = s[t]-sum;
    #pragma unroll
    for (int i=0;i<4;i++){ int idx=t*4+i; if (idx<nb) blksum[idx]=te+v[i]; }
}
__global__ __launch_bounds__(256) void k_scanC(int* __restrict__ a, int M, const int* __restrict__ blksum){
    int add = blksum[blockIdx.x];
    int base = blockIdx.x*STILE + threadIdx.x*SEPT;
    #pragma unroll
    for (int i=0;i<SEPT;i++){ int idx=base+i; if (idx<M) a[idx]+=add; }
}

__global__ __launch_bounds__(256) void k_scatter(const int* __restrict__ ei, int E,
        int B, int C, int shift, const int* __restrict__ scanT,
        uint32_t* __restrict__ tempD, uint16_t* __restrict__ tempS){
    __shared__ int cd[MAXB], cs[MAXB];
    int t = threadIdx.x, c = blockIdx.x;
    const int* row = scanT + (size_t)c*2*B;
    for (int i=t;i<B;i+=256){ cd[i] = row[i]; cs[i] = row[B+i] - E; }
    __syncthreads();
    int e0 = c*CHUNK, e1 = min(E, e0+CHUNK);
    int lmask = (1<<shift) - 1;
    for (int e = e0+t; e < e1; e += 256){
        int s = ei[e], d = ei[E+e];
        int p = atomicAdd(&cd[d>>shift], 1);
        tempD[p] = ((uint32_t)(d & lmask) << 20) | (uint32_t)s;
        int q = atomicAdd(&cs[s>>shift], 1);
        tempS[q] = (uint16_t)s;
    }
}

__global__ __launch_bounds__(256) void k_build2(const uint32_t* __restrict__ tempD,
        const uint16_t* __restrict__ tempS, const int* __restrict__ scan,
        int B, int C, int shift, int E, int N,
        int* __restrict__ row_off, int* __restrict__ csr, int* __restrict__ deg_out){
    __shared__ int cnt[MAXB];
    __shared__ int offl[MAXB];
    int b = blockIdx.x, t = threadIdx.x;
    int range = 1<<shift, nb0 = b<<shift;
    int seg0 = scan[(size_t)b*C];
    int seg1 = (b+1<B) ? scan[(size_t)(b+1)*C] : E;
    for (int i=t;i<range;i+=256) cnt[i]=0;
    __syncthreads();
    for (int i=seg0+t; i<seg1; i+=256)
        atomicAdd(&cnt[tempD[i]>>20], 1);
    __syncthreads();
    if (t==0){ int run=0; for (int i=0;i<range;i++){ offl[i]=run; run+=cnt[i]; } }
    __syncthreads();
    for (int i=t;i<range;i+=256){
        int node = nb0+i;
        if (node < N) row_off[node] = seg0 + offl[i];
    }
    if (b==B-1 && t==0) row_off[N] = E;
    for (int i=t;i<range;i+=256) cnt[i] = offl[i];
    __syncthreads();
    for (int i=seg0+t; i<seg1; i+=256){
        uint32_t v = tempD[i];
        int p = atomicAdd(&cnt[v>>20], 1);
        csr[seg0 + p] = (int)(v & 0xFFFFFu);
    }
    __syncthreads();
    int sg0 = scan[(size_t)(B+b)*C] - E;
    int sg1 = ((b+1<B) ? scan[(size_t)(B+b+1)*C] : 2*E) - E;
    for (int i=t;i<range;i+=256) cnt[i]=0;
    __syncthreads();
    for (int i=sg0+t; i<sg1; i+=256)
        atomicAdd(&cnt[(int)tempS[i] - nb0], 1);
    __syncthreads();
    for (int i=t;i<range;i+=256){
        int node = nb0+i;
        if (node < N) deg_out[node] = cnt[i];
    }
}

// ============ GEMM (swapped-operand MFMA) -> fp8 output ============
// out8[row][col] = fp8( (A[row,:] @ W)[col] * rsqrt(max(deg_out[row],1)) )
__global__ __launch_bounds__(256) void k_gemm(const void* __restrict__ A,
        const uint16_t* __restrict__ Wf, const int* __restrict__ deg_out,
        uint8_t* __restrict__ out8, int nrows, int amode){
    int t = threadIdx.x;
    int wave = t>>6, lane = t&63, quad = lane>>4, low = lane&15;

    int rowA  = blockIdx.x*64 + wave*16 + low;
    int rowAc = min(rowA, nrows-1);

    bf16x8 ah[4];
    if (amode){
        const uint16_t* arow = (const uint16_t*)A + (size_t)rowAc*FD;
        #pragma unroll
        for (int kk=0;kk<4;kk++)
            ah[kk] = *(const bf16x8*)(arow + kk*32 + quad*8);
    } else {
        const float* arow = (const float*)A + (size_t)rowAc*FD;
        #pragma unroll
        for (int kk=0;kk<4;kk++){
            f32x4 f0 = *(const f32x4*)(arow + kk*32 + quad*8);
            f32x4 f1 = *(const f32x4*)(arow + kk*32 + quad*8 + 4);
            #pragma unroll
            for (int j=0;j<4;j++) ah[kk][j]   = (short)f2bf(f0[j]);
            #pragma unroll
            for (int j=0;j<4;j++) ah[kk][j+4] = (short)f2bf(f1[j]);
        }
    }

    f32x4 acc[8];
    #pragma unroll
    for (int n=0;n<8;n++) acc[n] = (f32x4){0.f,0.f,0.f,0.f};

    #pragma unroll
    for (int kk=0;kk<4;kk++){
        #pragma unroll
        for (int n=0;n<8;n++){
            bf16x8 bh = *(const bf16x8*)(Wf + ((size_t)((kk*8+n)*64 + lane))*8);
            acc[n] = __builtin_amdgcn_mfma_f32_16x16x32_bf16(bh, ah[kk], acc[n], 0, 0, 0);
        }
    }

    if (rowA < nrows){
        float sc = rsqrtf((float)max(deg_out[rowA], 1));
        uint8_t* orow = out8 + (size_t)rowA*FD;
        #pragma unroll
        for (int n=0;n<8;n++){
            uint32_t pk = pk4fp8(acc[n][0]*sc, acc[n][1]*sc, acc[n][2]*sc, acc[n][3]*sc);
            *(uint32_t*)(orow + n*16 + quad*4) = pk;
        }
    }
}

// ============ SpMM (fp8 gather): full wave per node, 2 edges/iter ============
// lanes 0-31 = edge j, lanes 32-63 = edge j+1; lane owns 4 fp8 feats (4 B).
__global__ __launch_bounds__(256) void k_spmm(const uint8_t* __restrict__ tmp8,
        const int* __restrict__ row_off, const int* __restrict__ csr_src,
        const float* __restrict__ bias, uint16_t* __restrict__ hout, int N){
    int node = blockIdx.x*4 + (threadIdx.x>>6);
    int lane = threadIdx.x & 63;
    int l = lane & 31, half = lane >> 5;
    if (node >= N) return;
    int e0 = row_off[node], e1 = row_off[node+1];
    const uint32_t* tp = (const uint32_t*)tmp8;
    f32x2 a01 = {0.f,0.f}, a23 = {0.f,0.f};
    for (int base = e0; base < e1; base += 64){
        int my = 0;
        if (base + lane < e1) my = csr_src[base + lane];
        int cnt = min(64, e1 - base);
        int j = 0;
        for (; j + 8 <= cnt; j += 8){
            int s0 = __shfl(my, j   + half);
            int s1 = __shfl(my, j+2 + half);
            int s2 = __shfl(my, j+4 + half);
            int s3 = __shfl(my, j+6 + half);
            uint32_t p0 = tp[(size_t)s0*32 + l];
            uint32_t p1 = tp[(size_t)s1*32 + l];
            uint32_t p2 = tp[(size_t)s2*32 + l];
            uint32_t p3 = tp[(size_t)s3*32 + l];
            a01 += fp8lo2f(p0); a23 += fp8hi2f(p0);
            a01 += fp8lo2f(p1); a23 += fp8hi2f(p1);
            a01 += fp8lo2f(p2); a23 += fp8hi2f(p2);
            a01 += fp8lo2f(p3); a23 += fp8hi2f(p3);
        }
        for (; j < cnt; j += 2){
            int idx = j + half;
            int s = __shfl(my, (idx < cnt) ? idx : j);
            uint32_t p = tp[(size_t)s*32 + l];
            if (idx < cnt){ a01 += fp8lo2f(p); a23 += fp8hi2f(p); }
        }
    }
    a01.x += __shfl_xor(a01.x, 32);
    a01.y += __shfl_xor(a01.y, 32);
    a23.x += __shfl_xor(a23.x, 32);
    a23.y += __shfl_xor(a23.y, 32);
    if (half == 0){
        float isq = rsqrtf((float)max(e1 - e0, 1));
        f32x4 bs = *(const f32x4*)(bias + l*4);
        float r0 = fmaxf(a01.x*isq + bs[0], 0.f);
        float r1 = fmaxf(a01.y*isq + bs[1], 0.f);
        float r2 = fmaxf(a23.x*isq + bs[2], 0.f);
        float r3 = fmaxf(a23.y*isq + bs[3], 0.f);
        uint2 o;
        o.x = (uint32_t)f2bf(r0) | ((uint32_t)f2bf(r1) << 16);
        o.y = (uint32_t)f2bf(r2) | ((uint32_t)f2bf(r3) << 16);
        *(uint2*)(hout + (size_t)node*FD + l*4) = o;
    }
}

// ============ pool / final ============
__global__ __launch_bounds__(256) void k_pool(const uint16_t* __restrict__ h,
        const int* __restrict__ n2g, int N, float* __restrict__ pool){
    __shared__ float sacc[NG*FD];
    int t = threadIdx.x;
    for (int i = t; i < NG*FD; i += 256) sacc[i] = 0.f;
    __syncthreads();
    int fp = t & 63;
    int no = t >> 6;
    const uint32_t* hp = (const uint32_t*)h;
    float r0 = 0.f, r1 = 0.f; int rg = -1;
    int base = blockIdx.x * 64;
    #pragma unroll
    for (int i = 0; i < 16; i++){
        int node = base + i*4 + no;
        if (node < N){
            int g = n2g[node];
            if (g != rg){
                if (rg >= 0){
                    atomicAdd(&sacc[rg*FD + fp*2],     r0);
                    atomicAdd(&sacc[rg*FD + fp*2 + 1], r1);
                }
                r0 = r1 = 0.f; rg = g;
            }
            uint32_t p = hp[(size_t)node*64 + fp];
            r0 += bf2f((uint16_t)(p & 0xffff));
            r1 += bf2f((uint16_t)(p >> 16));
        }
    }
    if (rg >= 0){
        atomicAdd(&sacc[rg*FD + fp*2],     r0);
        atomicAdd(&sacc[rg*FD + fp*2 + 1], r1);
    }
    __syncthreads();
    for (int i = t; i < NG*FD; i += 256){
        float v = sacc[i];
        if (v != 0.f) atomicAdd(&pool[i], v);
    }
}

__global__ __launch_bounds__(128) void k_final(const float* __restrict__ pool,
        const int* __restrict__ n2g, int N, const float* __restrict__ Wl,
        const float* __restrict__ bl, float* __restrict__ out){
    __shared__ int ub[NG+1];
    __shared__ float logits[NG][NC];
    int t = threadIdx.x;
    if (t <= NG){
        int lo = 0, hi = N;
        while (lo < hi){ int mid = (lo+hi)>>1; if (n2g[mid] < t) lo = mid+1; else hi = mid; }
        ub[t] = lo;
    }
    __syncthreads();
    if (t < NG*NC){
        int g = t/NC, c = t%NC;
        float cnt = (float)max(ub[g+1]-ub[g], 1);
        float inv = 1.f/cnt;
        float acc = bl[c];
        for (int d=0; d<FD; d++)
            acc += pool[g*FD+d]*inv * Wl[d*NC+c];
        logits[g][c] = acc;
    }
    __syncthreads();
    if (t < NG*NC){
        int g = t/NC, c = t%NC;
        float m = -1e30f;
        for (int i=0;i<NC;i++) m = fmaxf(m, logits[g][i]);
        float ssum = 0.f;
        for (int i=0;i<NC;i++) ssum += expf(logits[g][i]-m);
        out[t] = expf(logits[g][c]-m)/ssum;
    }
}

extern "C" void kernel_launch(void* const* d_in, const int* in_sizes, int n_in,
                              void* d_out, int out_size, void* d_ws, size_t ws_size,
                              hipStream_t stream) {
    const float* x   = (const float*)d_in[0];
    const int*   ei  = (const int*)d_in[1];
    const int*   n2g = (const int*)d_in[2];
    const float* W1  = (const float*)d_in[3];
    const float* b1  = (const float*)d_in[4];
    const float* W2  = (const float*)d_in[5];
    const float* b2  = (const float*)d_in[6];
    const float* Wl  = (const float*)d_in[7];
    const float* bl  = (const float*)d_in[8];
    float* outp = (float*)d_out;

    int N = in_sizes[2];
    int E = in_sizes[1] / 2;

    int shift = 6;
    while ((((N + (1<<shift) - 1) >> shift) > MAXB) && shift < 10) shift++;
    int B = (N + (1<<shift) - 1) >> shift;
    int C = (E + CHUNK - 1) / CHUNK;
    int M = 2*B*C;

    char* w = (char*)d_ws;
    size_t off = 0;
    auto alloc = [&](size_t bytes)->char*{ char* p = w + off; off += (bytes + 255) & ~(size_t)255; return p; };
    float*    pool    = (float*)alloc((size_t)NG*FD*4);
    size_t zbytes = off;
    int*      deg_out = (int*)alloc((size_t)N*4);
    int*      row_off = (int*)alloc((size_t)(N+1)*4);
    int*      csr     = (int*)alloc((size_t)E*4);
    int*      blksum  = (int*)alloc(1024*4);
    uint16_t* Wf1     = (uint16_t*)alloc(16384*2);
    uint16_t* Wf2     = (uint16_t*)alloc(16384*2);
    uint8_t*  tmp8    = (uint8_t*)alloc((size_t)N*FD);      // fp8 gather buffer
    uint16_t* hb      = (uint16_t*)alloc((size_t)N*FD*2);
    (void)ws_size;
    // aliases (live only during CSR build, before tmp8/hb are written)
    uint32_t* tempD = (uint32_t*)tmp8;                      // E*4 <= N*FD
    uint16_t* tempS = (uint16_t*)(tmp8 + (size_t)E*4);      // +E*2
    size_t szM = ((size_t)M*4 + 255) & ~(size_t)255;
    int* cntT = (int*)hb;
    int* cnt  = (int*)((char*)hb + szM);

    hipMemsetAsync(d_ws, 0, zbytes, stream);

    int nblkA = (M + STILE - 1) / STILE;
    dim3 tg1((2*B + 31)/32, (C + 31)/32);
    dim3 tg2((C + 31)/32, (2*B + 31)/32);
    k_prep_w   <<<128, 256, 0, stream>>>(W1, W2, Wf1, Wf2);
    k_count    <<<C, 256, 0, stream>>>(ei, E, B, C, shift, cntT);
    k_transpose<<<tg1, 256, 0, stream>>>(cntT, cnt, C, 2*B);
    k_scanA    <<<nblkA, 256, 0, stream>>>(cnt, M, blksum);
    k_scanB    <<<1, 256, 0, stream>>>(blksum, nblkA);
    k_scanC    <<<nblkA, 256, 0, stream>>>(cnt, M, blksum);
    k_transpose<<<tg2, 256, 0, stream>>>(cnt, cntT, 2*B, C);
    k_scatter  <<<C, 256, 0, stream>>>(ei, E, B, C, shift, cntT, tempD, tempS);
    k_build2   <<<B, 256, 0, stream>>>(tempD, tempS, cnt, B, C, shift, E, N, row_off, csr, deg_out);

    int gb = (N + 63)/64;
    int sb = (N + 3)/4;
    int pb = (N + 63)/64;
    k_gemm <<<gb, 256, 0, stream>>>(x,  Wf1, deg_out, tmp8, N, 0);
    k_spmm <<<sb, 256, 0, stream>>>(tmp8, row_off, csr, b1, hb, N);
    k_gemm <<<gb, 256, 0, stream>>>(hb, Wf2, deg_out, tmp8, N, 1);
    k_spmm <<<sb, 256, 0, stream>>>(tmp8, row_off, csr, b2, hb, N);
    k_pool <<<pb, 256, 0, stream>>>(hb, n2g, N, pool);
    k_final<<<1,  128, 0, stream>>>(pool, n2g, N, Wl, bl, outp);
}